// Round 2
// baseline (8011.090 us; speedup 1.0000x reference)
//
#include <hip/hip_runtime.h>
#include <hip/hip_bf16.h>

#define NN 100000
#define NE 300000
#define NG 2000
#define DD 256
#define NL 5
#define BN_EPS 1e-5f

// ---------------- utility: zero / copy (avoid hipMemset/MemcpyAsync in capture) ----
__global__ __launch_bounds__(256) void k_zero4(float4* __restrict__ p, int n4) {
  int i = blockIdx.x * 256 + threadIdx.x;
  if (i < n4) p[i] = make_float4(0.f, 0.f, 0.f, 0.f);
}
__global__ __launch_bounds__(256) void k_copy4(float4* __restrict__ d,
                                               const float4* __restrict__ s, int n4) {
  int i = blockIdx.x * 256 + threadIdx.x;
  if (i < n4) d[i] = s[i];
}

// ---------------- node encode: h = x @ node_w + node_b, x is [NN,20] ----------------
__global__ __launch_bounds__(256) void k_node_encode(
    const float* __restrict__ x, const float* __restrict__ w,
    const float* __restrict__ b, float* __restrict__ h) {
  int n = blockIdx.x, d = threadIdx.x;
  __shared__ float xr[20];
  if (d < 20) xr[d] = x[n * 20 + d];
  __syncthreads();
  float s = b[d];
#pragma unroll
  for (int k = 0; k < 20; ++k) s = fmaf(xr[k], w[k * DD + d], s);
  h[(size_t)n * DD + d] = s;
}

// ---------------- vn init: vn[g][d] = vn_w[d] ----------------
__global__ __launch_bounds__(256) void k_vn_init(const float* __restrict__ vnw,
                                                 float* __restrict__ vn) {
  int i = blockIdx.x * 256 + threadIdx.x;
  vn[i] = vnw[i & (DD - 1)];
}

// ---------------- h += vn[batch] ----------------
__global__ __launch_bounds__(256) void k_add_vn(float* __restrict__ h,
                                                const float* __restrict__ vn,
                                                const int* __restrict__ batch) {
  int idx = blockIdx.x * 256 + threadIdx.x;  // float4 index
  int n = idx >> 6, c = idx & 63;
  float4 hv = ((float4*)h)[idx];
  float4 v = ((const float4*)vn)[(size_t)batch[n] * 64 + c];
  hv.x += v.x; hv.y += v.y; hv.z += v.z; hv.w += v.w;
  ((float4*)h)[idx] = hv;
}

// ---------------- edge scatter: agg[dst] += h[src]; one wave per edge ----------------
__global__ __launch_bounds__(256) void k_edge_scatter(
    const int* __restrict__ src, const int* __restrict__ dst,
    const float* __restrict__ h, float* __restrict__ agg) {
  int e = blockIdx.x * 4 + (threadIdx.x >> 6);
  if (e >= NE) return;
  int lane = threadIdx.x & 63;
  int s = src[e], t = dst[e];
  float4 v = ((const float4*)h)[(size_t)s * 64 + lane];
  float* a = agg + (size_t)t * DD + lane * 4;
  atomicAdd(a + 0, v.x);
  atomicAdd(a + 1, v.y);
  atomicAdd(a + 2, v.z);
  atomicAdd(a + 3, v.w);
}

// ---------------- pooling: out[batch[n]] += h[n], run-length to cut atomics -------
__global__ __launch_bounds__(256) void k_pool(const float* __restrict__ h,
                                              const int* __restrict__ batch,
                                              float* __restrict__ out) {
  const int CH = 128;
  int n0 = blockIdx.x * CH;
  int d = threadIdx.x;
  __shared__ int bs[CH];
  for (int i = threadIdx.x; i < CH; i += 256) {
    int n = n0 + i;
    bs[i] = (n < NN) ? batch[n] : -1;
  }
  __syncthreads();
  int nmax = min(CH, NN - n0);
  float acc = 0.f;
  int cur = bs[0];
  for (int i = 0; i < nmax; ++i) {
    int g = bs[i];
    if (g != cur) {
      atomicAdd(&out[(size_t)cur * DD + d], acc);
      acc = 0.f;
      cur = g;
    }
    acc += h[(size_t)(n0 + i) * DD + d];
  }
  atomicAdd(&out[(size_t)cur * DD + d], acc);
}

// ---------------- big GEMM: full-N stripe per block so GEMM1 can run IN-PLACE -----
// C[m0:m0+64, 0:256] = epi((A [+A2]) @ W + bias)
// ADD2: A := A + A2 on load.  BNLEAKY: bn+leaky(0.1) epilogue, else relu.
// In-place safety (C == A2): each block reads only rows [m0,m0+64) of A2 (done
// before last barrier) and writes only those rows; no cross-block overlap.
template <bool ADD2, bool BNLEAKY>
__global__ __launch_bounds__(256) void k_gemm64x256(
    const float* __restrict__ A, const float* __restrict__ A2,
    const float* __restrict__ W, const float* __restrict__ bias,
    const float* __restrict__ bng, const float* __restrict__ bnb,
    const float* __restrict__ bnm, const float* __restrict__ bnv,
    float* __restrict__ C) {
  __shared__ float As[32][68];   // [k][m], padded
  __shared__ float Bs[32][260];  // [k][n], padded
  int tid = threadIdx.x;
  int tx = tid & 63;   // col group: cols tx*4 .. +3
  int ty = tid >> 6;   // row group: rows ty*16 .. +15
  int m0 = blockIdx.x * 64;
  float acc[16][4] = {};
  for (int k0 = 0; k0 < DD; k0 += 32) {
    // A tile: 64 rows x 32 k = 512 float4, 2 per thread
#pragma unroll
    for (int i = 0; i < 2; ++i) {
      int id = i * 256 + tid;
      int row = id >> 3, kc = (id & 7) << 2;
      int m = m0 + row;
      float4 v = make_float4(0.f, 0.f, 0.f, 0.f);
      if (m < NN) {
        v = *(const float4*)(A + (size_t)m * DD + k0 + kc);
        if (ADD2) {
          float4 u = *(const float4*)(A2 + (size_t)m * DD + k0 + kc);
          v.x += u.x; v.y += u.y; v.z += u.z; v.w += u.w;
        }
      }
      As[kc + 0][row] = v.x;
      As[kc + 1][row] = v.y;
      As[kc + 2][row] = v.z;
      As[kc + 3][row] = v.w;
    }
    // B tile: 32 rows x 256 cols = 2048 float4, 8 per thread
#pragma unroll
    for (int i = 0; i < 8; ++i) {
      int id = i * 256 + tid;
      int row = id >> 6, c4 = (id & 63) << 2;
      *(float4*)&Bs[row][c4] = *(const float4*)(W + (size_t)(k0 + row) * DD + c4);
    }
    __syncthreads();
#pragma unroll
    for (int kk = 0; kk < 32; ++kk) {
      float4 b4 = *(float4*)&Bs[kk][tx << 2];
      float bb[4] = {b4.x, b4.y, b4.z, b4.w};
#pragma unroll
      for (int r4 = 0; r4 < 4; ++r4) {
        float4 a4 = *(float4*)&As[kk][(ty << 4) + (r4 << 2)];
        float aa[4] = {a4.x, a4.y, a4.z, a4.w};
#pragma unroll
        for (int i = 0; i < 4; ++i)
#pragma unroll
          for (int j = 0; j < 4; ++j)
            acc[r4 * 4 + i][j] = fmaf(aa[i], bb[j], acc[r4 * 4 + i][j]);
      }
    }
    __syncthreads();
  }
  // epilogue
  int nb = tx << 2;
  float sc[4], sh[4];
#pragma unroll
  for (int j = 0; j < 4; ++j) {
    int n = nb + j;
    float bsv = bias[n];
    if (BNLEAKY) {
      float s = bng[n] * rsqrtf(bnv[n] + BN_EPS);
      sc[j] = s;
      sh[j] = bsv * s + bnb[n] - bnm[n] * s;
    } else {
      sc[j] = 1.f;
      sh[j] = bsv;
    }
  }
#pragma unroll
  for (int r = 0; r < 16; ++r) {
    int m = m0 + (ty << 4) + r;
    if (m < NN) {
      float vv[4];
#pragma unroll
      for (int j = 0; j < 4; ++j) {
        float v = acc[r][j] * sc[j] + sh[j];
        if (BNLEAKY) v = (v > 0.f) ? v : 0.1f * v;
        else v = fmaxf(v, 0.f);
        vv[j] = v;
      }
      *(float4*)(C + (size_t)m * DD + nb) = make_float4(vv[0], vv[1], vv[2], vv[3]);
    }
  }
}

// ---------------- small GEMM, one block per row ----------------
// MODE 0: bias + relu; MODE 1: bias + bn + relu; MODE 2: bias only
template <int MODE>
__global__ __launch_bounds__(256) void k_gemm_row(
    const float* __restrict__ X, const float* __restrict__ W,
    const float* __restrict__ bias,
    const float* __restrict__ bng, const float* __restrict__ bnb,
    const float* __restrict__ bnm, const float* __restrict__ bnv,
    float* __restrict__ Y, int K, int N) {
  __shared__ float xs[DD];
  int m = blockIdx.x;
  for (int k = threadIdx.x; k < K; k += 256) xs[k] = X[(size_t)m * K + k];
  __syncthreads();
  for (int n = threadIdx.x; n < N; n += 256) {
    float s = bias[n];
    for (int k = 0; k < K; ++k) s = fmaf(xs[k], W[(size_t)k * N + n], s);
    if (MODE == 1) {
      float scl = bng[n] * rsqrtf(bnv[n] + BN_EPS);
      s = s * scl + (bnb[n] - bnm[n] * scl);
    }
    if (MODE <= 1) s = fmaxf(s, 0.f);
    Y[(size_t)m * N + n] = s;
  }
}

extern "C" void kernel_launch(void* const* d_in, const int* in_sizes, int n_in,
                              void* d_out, int out_size, void* d_ws, size_t ws_size,
                              hipStream_t stream) {
  const float* x      = (const float*)d_in[0];
  const int*   ei     = (const int*)d_in[1];
  const int*   batch  = (const int*)d_in[2];
  const float* node_w = (const float*)d_in[3];
  const float* node_b = (const float*)d_in[4];
  const float* vn_w   = (const float*)d_in[5];
  const float* gin_w1 = (const float*)d_in[6];
  const float* gin_b1 = (const float*)d_in[7];
  const float* gin_w2 = (const float*)d_in[8];
  const float* gin_b2 = (const float*)d_in[9];
  const float* bn_g   = (const float*)d_in[10];
  const float* bn_b   = (const float*)d_in[11];
  const float* bn_m   = (const float*)d_in[12];
  const float* bn_v   = (const float*)d_in[13];
  const float* vn_w1  = (const float*)d_in[14];
  const float* vn_b1  = (const float*)d_in[15];
  const float* vbn1g  = (const float*)d_in[16];
  const float* vbn1b  = (const float*)d_in[17];
  const float* vbn1m  = (const float*)d_in[18];
  const float* vbn1v  = (const float*)d_in[19];
  const float* vn_w2  = (const float*)d_in[20];
  const float* vn_b2  = (const float*)d_in[21];
  const float* vbn2g  = (const float*)d_in[22];
  const float* vbn2b  = (const float*)d_in[23];
  const float* vbn2m  = (const float*)d_in[24];
  const float* vbn2v  = (const float*)d_in[25];
  const float* head_w1 = (const float*)d_in[26];
  const float* head_b1 = (const float*)d_in[27];
  const float* head_w2 = (const float*)d_in[28];
  const float* head_b2 = (const float*)d_in[29];
  const float* head_w3 = (const float*)d_in[30];
  const float* head_b3 = (const float*)d_in[31];

  // workspace layout (~212 MB total)
  float* ws  = (float*)d_ws;
  float* h   = ws;                       // [NN, DD]  102.4 MB
  float* agg = h + (size_t)NN * DD;      // [NN, DD]  102.4 MB (also GIN-MLP hidden, in place)
  float* vn  = agg + (size_t)NN * DD;    // [NG, DD]
  float* t0  = vn + (size_t)NG * DD;     // [NG, DD]
  float* t1  = t0 + (size_t)NG * DD;     // [NG, DD]
  float* gh1 = t1 + (size_t)NG * DD;     // [NG, 128]
  float* gh2 = gh1 + (size_t)NG * 128;   // [NG, 64]

  const int* src = ei;
  const int* dst = ei + NE;

  const int NND4 = NN * DD / 4;   // 6,400,000
  const int NGD4 = NG * DD / 4;   // 128,000

  k_node_encode<<<NN, 256, 0, stream>>>(x, node_w, node_b, h);
  k_vn_init<<<NG * DD / 256, 256, 0, stream>>>(vn_w, vn);

  for (int l = 0; l < NL; ++l) {
    k_add_vn<<<NND4 / 256, 256, 0, stream>>>(h, vn, batch);
    k_zero4<<<(NND4 + 255) / 256, 256, 0, stream>>>((float4*)agg, NND4);
    k_edge_scatter<<<(NE + 3) / 4, 256, 0, stream>>>(src, dst, h, agg);
    // agg = relu((h + agg) @ W1 + b1)   [in place]
    k_gemm64x256<true, false><<<(NN + 63) / 64, 256, 0, stream>>>(
        h, agg, gin_w1 + (size_t)l * DD * DD, gin_b1 + l * DD,
        nullptr, nullptr, nullptr, nullptr, agg);
    // h = leaky(bn(agg @ W2 + b2))
    k_gemm64x256<false, true><<<(NN + 63) / 64, 256, 0, stream>>>(
        agg, nullptr, gin_w2 + (size_t)l * DD * DD, gin_b2 + l * DD,
        bn_g + l * DD, bn_b + l * DD, bn_m + l * DD, bn_v + l * DD, h);
    if (l < NL - 1) {
      k_copy4<<<(NGD4 + 255) / 256, 256, 0, stream>>>((float4*)t0, (const float4*)vn, NGD4);
      k_pool<<<(NN + 127) / 128, 256, 0, stream>>>(h, batch, t0);
      k_gemm_row<1><<<NG, 256, 0, stream>>>(
          t0, vn_w1 + (size_t)l * DD * DD, vn_b1 + l * DD,
          vbn1g + l * DD, vbn1b + l * DD, vbn1m + l * DD, vbn1v + l * DD,
          t1, DD, DD);
      k_gemm_row<1><<<NG, 256, 0, stream>>>(
          t1, vn_w2 + (size_t)l * DD * DD, vn_b2 + l * DD,
          vbn2g + l * DD, vbn2b + l * DD, vbn2m + l * DD, vbn2v + l * DD,
          vn, DD, DD);
    }
  }
  k_zero4<<<(NGD4 + 255) / 256, 256, 0, stream>>>((float4*)t0, NGD4);
  k_pool<<<(NN + 127) / 128, 256, 0, stream>>>(h, batch, t0);
  k_gemm_row<0><<<NG, 256, 0, stream>>>(
      t0, head_w1, head_b1, nullptr, nullptr, nullptr, nullptr, gh1, DD, 128);
  k_gemm_row<0><<<NG, 256, 0, stream>>>(
      gh1, head_w2, head_b2, nullptr, nullptr, nullptr, nullptr, gh2, 128, 64);
  k_gemm_row<2><<<NG, 256, 0, stream>>>(
      gh2, head_w3, head_b3, nullptr, nullptr, nullptr, nullptr, (float*)d_out, 64, 11);
}

// Round 3
// 3405.015 us; speedup vs baseline: 2.3527x; 2.3527x over previous
//
#include <hip/hip_runtime.h>
#include <hip/hip_bf16.h>

#define NN 100000
#define NE 300000
#define NG 2000
#define DD 256
#define NL 5
#define BN_EPS 1e-5f

// ---------------- utility ----------------
__global__ __launch_bounds__(256) void k_zero4(float4* __restrict__ p, int n4) {
  int i = blockIdx.x * 256 + threadIdx.x;
  if (i < n4) p[i] = make_float4(0.f, 0.f, 0.f, 0.f);
}
__global__ __launch_bounds__(256) void k_copy4(float4* __restrict__ d,
                                               const float4* __restrict__ s, int n4) {
  int i = blockIdx.x * 256 + threadIdx.x;
  if (i < n4) d[i] = s[i];
}
__global__ __launch_bounds__(256) void k_zeroi(int* __restrict__ p, int n) {
  int i = blockIdx.x * 256 + threadIdx.x;
  if (i < n) p[i] = 0;
}

// ---------------- CSR build: histogram by dst ----------------
__global__ __launch_bounds__(256) void k_hist(const int* __restrict__ dst,
                                              int* __restrict__ cnt) {
  int e = blockIdx.x * 256 + threadIdx.x;
  if (e < NE) atomicAdd(&cnt[dst[e]], 1);
}

// single-block exclusive scan of cnt[NN] -> rowptr, cursor
__global__ __launch_bounds__(1024) void k_scan(const int* __restrict__ cnt,
                                               int* __restrict__ rowptr,
                                               int* __restrict__ cursor) {
  const int T = 1024;
  const int PER = (NN + T - 1) / T;  // 98
  __shared__ int part[T];
  int t = threadIdx.x;
  int base = t * PER;
  int s = 0;
  for (int i = 0; i < PER; ++i) {
    int idx = base + i;
    if (idx < NN) s += cnt[idx];
  }
  part[t] = s;
  __syncthreads();
  // Hillis-Steele inclusive scan
  for (int off = 1; off < T; off <<= 1) {
    int v = part[t];
    int add = (t >= off) ? part[t - off] : 0;
    __syncthreads();
    part[t] = v + add;
    __syncthreads();
  }
  int run = (t == 0) ? 0 : part[t - 1];
  for (int i = 0; i < PER; ++i) {
    int idx = base + i;
    if (idx < NN) {
      rowptr[idx] = run;
      cursor[idx] = run;
      run += cnt[idx];
    }
  }
  if (t == 0) rowptr[NN] = NE;
}

// scatter src ids into dst-sorted order
__global__ __launch_bounds__(256) void k_fill_src(const int* __restrict__ src,
                                                  const int* __restrict__ dst,
                                                  int* __restrict__ cursor,
                                                  int* __restrict__ ssrc) {
  int e = blockIdx.x * 256 + threadIdx.x;
  if (e >= NE) return;
  int pos = atomicAdd(&cursor[dst[e]], 1);
  ssrc[pos] = src[e];
}

// ---------------- aggregate: one wave per node, agg[n] = sum_{e in CSR[n]} h[ssrc[e]] ----
__global__ __launch_bounds__(256) void k_aggregate(
    const float4* __restrict__ h4, const int* __restrict__ rowptr,
    const int* __restrict__ ssrc, float4* __restrict__ out4) {
  int node = blockIdx.x * 4 + (threadIdx.x >> 6);
  if (node >= NN) return;
  int lane = threadIdx.x & 63;
  int b = rowptr[node], e = rowptr[node + 1];
  float4 acc = make_float4(0.f, 0.f, 0.f, 0.f);
  for (int i = b; i < e; ++i) {
    int s = ssrc[i];
    float4 v = h4[(size_t)s * 64 + lane];
    acc.x += v.x; acc.y += v.y; acc.z += v.z; acc.w += v.w;
  }
  out4[(size_t)node * 64 + lane] = acc;
}

// ---------------- node encode: h = x @ node_w + node_b, x is [NN,20] ----------------
__global__ __launch_bounds__(256) void k_node_encode(
    const float* __restrict__ x, const float* __restrict__ w,
    const float* __restrict__ b, float* __restrict__ h) {
  int n = blockIdx.x, d = threadIdx.x;
  __shared__ float xr[20];
  if (d < 20) xr[d] = x[n * 20 + d];
  __syncthreads();
  float s = b[d];
#pragma unroll
  for (int k = 0; k < 20; ++k) s = fmaf(xr[k], w[k * DD + d], s);
  h[(size_t)n * DD + d] = s;
}

// ---------------- vn init ----------------
__global__ __launch_bounds__(256) void k_vn_init(const float* __restrict__ vnw,
                                                 float* __restrict__ vn) {
  int i = blockIdx.x * 256 + threadIdx.x;
  vn[i] = vnw[i & (DD - 1)];
}

// ---------------- h += vn[batch] ----------------
__global__ __launch_bounds__(256) void k_add_vn(float* __restrict__ h,
                                                const float* __restrict__ vn,
                                                const int* __restrict__ batch) {
  int idx = blockIdx.x * 256 + threadIdx.x;  // float4 index
  int n = idx >> 6, c = idx & 63;
  float4 hv = ((float4*)h)[idx];
  float4 v = ((const float4*)vn)[(size_t)batch[n] * 64 + c];
  hv.x += v.x; hv.y += v.y; hv.z += v.z; hv.w += v.w;
  ((float4*)h)[idx] = hv;
}

// ---------------- pooling: out[batch[n]] += h[n], run-length to cut atomics -------
__global__ __launch_bounds__(256) void k_pool(const float* __restrict__ h,
                                              const int* __restrict__ batch,
                                              float* __restrict__ out) {
  const int CH = 128;
  int n0 = blockIdx.x * CH;
  int d = threadIdx.x;
  __shared__ int bs[CH];
  for (int i = threadIdx.x; i < CH; i += 256) {
    int n = n0 + i;
    bs[i] = (n < NN) ? batch[n] : -1;
  }
  __syncthreads();
  int nmax = min(CH, NN - n0);
  float acc = 0.f;
  int cur = bs[0];
  for (int i = 0; i < nmax; ++i) {
    int g = bs[i];
    if (g != cur) {
      atomicAdd(&out[(size_t)cur * DD + d], acc);
      acc = 0.f;
      cur = g;
    }
    acc += h[(size_t)(n0 + i) * DD + d];
  }
  atomicAdd(&out[(size_t)cur * DD + d], acc);
}

// ---------------- big GEMM: full-N stripe per block; GEMM1 runs in place ----------
template <bool ADD2, bool BNLEAKY>
__global__ __launch_bounds__(256) void k_gemm64x256(
    const float* __restrict__ A, const float* __restrict__ A2,
    const float* __restrict__ W, const float* __restrict__ bias,
    const float* __restrict__ bng, const float* __restrict__ bnb,
    const float* __restrict__ bnm, const float* __restrict__ bnv,
    float* __restrict__ C) {
  __shared__ float As[32][68];   // [k][m], padded
  __shared__ float Bs[32][260];  // [k][n], padded
  int tid = threadIdx.x;
  int tx = tid & 63;   // col group: cols tx*4 .. +3
  int ty = tid >> 6;   // row group: rows ty*16 .. +15
  int m0 = blockIdx.x * 64;
  float acc[16][4] = {};
  for (int k0 = 0; k0 < DD; k0 += 32) {
#pragma unroll
    for (int i = 0; i < 2; ++i) {
      int id = i * 256 + tid;
      int row = id >> 3, kc = (id & 7) << 2;
      int m = m0 + row;
      float4 v = make_float4(0.f, 0.f, 0.f, 0.f);
      if (m < NN) {
        v = *(const float4*)(A + (size_t)m * DD + k0 + kc);
        if (ADD2) {
          float4 u = *(const float4*)(A2 + (size_t)m * DD + k0 + kc);
          v.x += u.x; v.y += u.y; v.z += u.z; v.w += u.w;
        }
      }
      As[kc + 0][row] = v.x;
      As[kc + 1][row] = v.y;
      As[kc + 2][row] = v.z;
      As[kc + 3][row] = v.w;
    }
#pragma unroll
    for (int i = 0; i < 8; ++i) {
      int id = i * 256 + tid;
      int row = id >> 6, c4 = (id & 63) << 2;
      *(float4*)&Bs[row][c4] = *(const float4*)(W + (size_t)(k0 + row) * DD + c4);
    }
    __syncthreads();
#pragma unroll
    for (int kk = 0; kk < 32; ++kk) {
      float4 b4 = *(float4*)&Bs[kk][tx << 2];
      float bb[4] = {b4.x, b4.y, b4.z, b4.w};
#pragma unroll
      for (int r4 = 0; r4 < 4; ++r4) {
        float4 a4 = *(float4*)&As[kk][(ty << 4) + (r4 << 2)];
        float aa[4] = {a4.x, a4.y, a4.z, a4.w};
#pragma unroll
        for (int i = 0; i < 4; ++i)
#pragma unroll
          for (int j = 0; j < 4; ++j)
            acc[r4 * 4 + i][j] = fmaf(aa[i], bb[j], acc[r4 * 4 + i][j]);
      }
    }
    __syncthreads();
  }
  int nb = tx << 2;
  float sc[4], sh[4];
#pragma unroll
  for (int j = 0; j < 4; ++j) {
    int n = nb + j;
    float bsv = bias[n];
    if (BNLEAKY) {
      float s = bng[n] * rsqrtf(bnv[n] + BN_EPS);
      sc[j] = s;
      sh[j] = bsv * s + bnb[n] - bnm[n] * s;
    } else {
      sc[j] = 1.f;
      sh[j] = bsv;
    }
  }
#pragma unroll
  for (int r = 0; r < 16; ++r) {
    int m = m0 + (ty << 4) + r;
    if (m < NN) {
      float vv[4];
#pragma unroll
      for (int j = 0; j < 4; ++j) {
        float v = acc[r][j] * sc[j] + sh[j];
        if (BNLEAKY) v = (v > 0.f) ? v : 0.1f * v;
        else v = fmaxf(v, 0.f);
        vv[j] = v;
      }
      *(float4*)(C + (size_t)m * DD + nb) = make_float4(vv[0], vv[1], vv[2], vv[3]);
    }
  }
}

// ---------------- small GEMM, one block per row ----------------
template <int MODE>
__global__ __launch_bounds__(256) void k_gemm_row(
    const float* __restrict__ X, const float* __restrict__ W,
    const float* __restrict__ bias,
    const float* __restrict__ bng, const float* __restrict__ bnb,
    const float* __restrict__ bnm, const float* __restrict__ bnv,
    float* __restrict__ Y, int K, int N) {
  __shared__ float xs[DD];
  int m = blockIdx.x;
  for (int k = threadIdx.x; k < K; k += 256) xs[k] = X[(size_t)m * K + k];
  __syncthreads();
  for (int n = threadIdx.x; n < N; n += 256) {
    float s = bias[n];
    for (int k = 0; k < K; ++k) s = fmaf(xs[k], W[(size_t)k * N + n], s);
    if (MODE == 1) {
      float scl = bng[n] * rsqrtf(bnv[n] + BN_EPS);
      s = s * scl + (bnb[n] - bnm[n] * scl);
    }
    if (MODE <= 1) s = fmaxf(s, 0.f);
    Y[(size_t)m * N + n] = s;
  }
}

extern "C" void kernel_launch(void* const* d_in, const int* in_sizes, int n_in,
                              void* d_out, int out_size, void* d_ws, size_t ws_size,
                              hipStream_t stream) {
  const float* x      = (const float*)d_in[0];
  const int*   ei     = (const int*)d_in[1];
  const int*   batch  = (const int*)d_in[2];
  const float* node_w = (const float*)d_in[3];
  const float* node_b = (const float*)d_in[4];
  const float* vn_w   = (const float*)d_in[5];
  const float* gin_w1 = (const float*)d_in[6];
  const float* gin_b1 = (const float*)d_in[7];
  const float* gin_w2 = (const float*)d_in[8];
  const float* gin_b2 = (const float*)d_in[9];
  const float* bn_g   = (const float*)d_in[10];
  const float* bn_b   = (const float*)d_in[11];
  const float* bn_m   = (const float*)d_in[12];
  const float* bn_v   = (const float*)d_in[13];
  const float* vn_w1  = (const float*)d_in[14];
  const float* vn_b1  = (const float*)d_in[15];
  const float* vbn1g  = (const float*)d_in[16];
  const float* vbn1b  = (const float*)d_in[17];
  const float* vbn1m  = (const float*)d_in[18];
  const float* vbn1v  = (const float*)d_in[19];
  const float* vn_w2  = (const float*)d_in[20];
  const float* vn_b2  = (const float*)d_in[21];
  const float* vbn2g  = (const float*)d_in[22];
  const float* vbn2b  = (const float*)d_in[23];
  const float* vbn2m  = (const float*)d_in[24];
  const float* vbn2v  = (const float*)d_in[25];
  const float* head_w1 = (const float*)d_in[26];
  const float* head_b1 = (const float*)d_in[27];
  const float* head_w2 = (const float*)d_in[28];
  const float* head_b2 = (const float*)d_in[29];
  const float* head_w3 = (const float*)d_in[30];
  const float* head_b3 = (const float*)d_in[31];

  float* ws  = (float*)d_ws;
  float* h   = ws;                       // [NN, DD]
  float* agg = h + (size_t)NN * DD;      // [NN, DD] (also GIN hidden, in place)
  float* vn  = agg + (size_t)NN * DD;    // [NG, DD]
  float* t0  = vn + (size_t)NG * DD;     // [NG, DD]
  float* t1  = t0 + (size_t)NG * DD;     // [NG, DD]
  float* gh1 = t1 + (size_t)NG * DD;     // [NG, 128]
  float* gh2 = gh1 + (size_t)NG * 128;   // [NG, 64]
  int* rowptr = (int*)(gh2 + (size_t)NG * 64);  // [NN+1]
  int* cursor = rowptr + NN + 1;                // [NN]
  int* ssrc   = cursor + NN;                    // [NE]

  const int* src = ei;
  const int* dst = ei + NE;

  const int NND4 = NN * DD / 4;
  const int NGD4 = NG * DD / 4;

  // ---- CSR build (once per launch) ----
  k_zeroi<<<(NN + 255) / 256, 256, 0, stream>>>(cursor, NN);  // reuse cursor as cnt
  k_hist<<<(NE + 255) / 256, 256, 0, stream>>>(dst, cursor);
  k_scan<<<1, 1024, 0, stream>>>(cursor, rowptr, cursor /*becomes running cursor*/);
  // note: k_scan reads cnt and writes cursor=rowptr copy; same buffer works because
  // each element is read (cnt) before being overwritten with the exclusive prefix.
  k_fill_src<<<(NE + 255) / 256, 256, 0, stream>>>(src, dst, cursor, ssrc);

  k_node_encode<<<NN, 256, 0, stream>>>(x, node_w, node_b, h);
  k_vn_init<<<NG * DD / 256, 256, 0, stream>>>(vn_w, vn);

  for (int l = 0; l < NL; ++l) {
    k_add_vn<<<NND4 / 256, 256, 0, stream>>>(h, vn, batch);
    k_aggregate<<<(NN + 3) / 4, 256, 0, stream>>>((const float4*)h, rowptr, ssrc,
                                                  (float4*)agg);
    // agg = relu((h + agg) @ W1 + b1)   [in place]
    k_gemm64x256<true, false><<<(NN + 63) / 64, 256, 0, stream>>>(
        h, agg, gin_w1 + (size_t)l * DD * DD, gin_b1 + l * DD,
        nullptr, nullptr, nullptr, nullptr, agg);
    // h = leaky(bn(agg @ W2 + b2))
    k_gemm64x256<false, true><<<(NN + 63) / 64, 256, 0, stream>>>(
        agg, nullptr, gin_w2 + (size_t)l * DD * DD, gin_b2 + l * DD,
        bn_g + l * DD, bn_b + l * DD, bn_m + l * DD, bn_v + l * DD, h);
    if (l < NL - 1) {
      k_copy4<<<(NGD4 + 255) / 256, 256, 0, stream>>>((float4*)t0, (const float4*)vn, NGD4);
      k_pool<<<(NN + 127) / 128, 256, 0, stream>>>(h, batch, t0);
      k_gemm_row<1><<<NG, 256, 0, stream>>>(
          t0, vn_w1 + (size_t)l * DD * DD, vn_b1 + l * DD,
          vbn1g + l * DD, vbn1b + l * DD, vbn1m + l * DD, vbn1v + l * DD,
          t1, DD, DD);
      k_gemm_row<1><<<NG, 256, 0, stream>>>(
          t1, vn_w2 + (size_t)l * DD * DD, vn_b2 + l * DD,
          vbn2g + l * DD, vbn2b + l * DD, vbn2m + l * DD, vbn2v + l * DD,
          vn, DD, DD);
    }
  }
  k_zero4<<<(NGD4 + 255) / 256, 256, 0, stream>>>((float4*)t0, NGD4);
  k_pool<<<(NN + 127) / 128, 256, 0, stream>>>(h, batch, t0);
  k_gemm_row<0><<<NG, 256, 0, stream>>>(
      t0, head_w1, head_b1, nullptr, nullptr, nullptr, nullptr, gh1, DD, 128);
  k_gemm_row<0><<<NG, 256, 0, stream>>>(
      gh1, head_w2, head_b2, nullptr, nullptr, nullptr, nullptr, gh2, 128, 64);
  k_gemm_row<2><<<NG, 256, 0, stream>>>(
      gh2, head_w3, head_b3, nullptr, nullptr, nullptr, nullptr, (float*)d_out, 64, 11);
}

// Round 4
// 1944.408 us; speedup vs baseline: 4.1201x; 1.7512x over previous
//
#include <hip/hip_runtime.h>
#include <hip/hip_bf16.h>

#define NN 100000
#define NE 300000
#define NG 2000
#define DD 256
#define NL 5
#define BN_EPS 1e-5f

typedef __bf16 bf16x8 __attribute__((ext_vector_type(8)));
typedef float floatx16 __attribute__((ext_vector_type(16)));

__device__ inline unsigned short f2bf(float x) {
  unsigned int u = __builtin_bit_cast(unsigned int, x);
  unsigned int r = u + 0x7FFFu + ((u >> 16) & 1u);
  return (unsigned short)(r >> 16);
}

// ---------------- utility ----------------
__global__ __launch_bounds__(256) void k_zero4(float4* __restrict__ p, int n4) {
  int i = blockIdx.x * 256 + threadIdx.x;
  if (i < n4) p[i] = make_float4(0.f, 0.f, 0.f, 0.f);
}
__global__ __launch_bounds__(256) void k_copy4(float4* __restrict__ d,
                                               const float4* __restrict__ s, int n4) {
  int i = blockIdx.x * 256 + threadIdx.x;
  if (i < n4) d[i] = s[i];
}
__global__ __launch_bounds__(256) void k_zeroi(int* __restrict__ p, int n) {
  int i = blockIdx.x * 256 + threadIdx.x;
  if (i < n) p[i] = 0;
}

// ---------------- weight pack: W[k][n] fp32 -> fragment-major bf16 ----------------
// Wf flat idx = ((nt*16 + ks)*64 + lane)*8 + j ; n = nt*32+(lane&31), k = ks*16+(lane>>5)*8+j
__global__ __launch_bounds__(256) void k_pack_w(const float* __restrict__ W,
                                                unsigned short* __restrict__ Wf,
                                                int nmat) {
  int idx = blockIdx.x * 256 + threadIdx.x;
  if (idx >= nmat * 65536) return;
  int m = idx >> 16, r = idx & 65535;
  int j = r & 7, lane = (r >> 3) & 63, ks = (r >> 9) & 15, nt = r >> 13;
  int n = nt * 32 + (lane & 31);
  int k = ks * 16 + ((lane >> 5) << 3) + j;
  Wf[idx] = f2bf(W[(size_t)m * 65536 + k * 256 + n]);
}

// ---------------- CSR build ----------------
__global__ __launch_bounds__(256) void k_hist(const int* __restrict__ dst,
                                              int* __restrict__ cnt) {
  int e = blockIdx.x * 256 + threadIdx.x;
  if (e < NE) atomicAdd(&cnt[dst[e]], 1);
}

// block sums of cnt (98 blocks x 1024)
__global__ __launch_bounds__(1024) void k_bsum(const int* __restrict__ cnt,
                                               int* __restrict__ bsum) {
  __shared__ int sh[1024];
  int t = threadIdx.x, idx = blockIdx.x * 1024 + t;
  sh[t] = (idx < NN) ? cnt[idx] : 0;
  __syncthreads();
  for (int off = 512; off > 0; off >>= 1) {
    if (t < off) sh[t] += sh[t + off];
    __syncthreads();
  }
  if (t == 0) bsum[blockIdx.x] = sh[0];
}

// tiny exclusive scan of 98 block sums
__global__ __launch_bounds__(128) void k_scanb(const int* __restrict__ bsum,
                                               int* __restrict__ bbase, int nb) {
  __shared__ int sh[128];
  int t = threadIdx.x;
  sh[t] = (t < nb) ? bsum[t] : 0;
  __syncthreads();
  if (t == 0) {
    int run = 0;
    for (int i = 0; i < nb; ++i) { int v = sh[i]; sh[i] = run; run += v; }
  }
  __syncthreads();
  if (t < nb) bbase[t] = sh[t];
}

// per-block exclusive scan + base -> rowptr, cursor
__global__ __launch_bounds__(1024) void k_rowptr(const int* __restrict__ cnt,
                                                 const int* __restrict__ bbase,
                                                 int* __restrict__ rowptr,
                                                 int* __restrict__ cursor) {
  __shared__ int sh[1024];
  int t = threadIdx.x, idx = blockIdx.x * 1024 + t;
  int v = (idx < NN) ? cnt[idx] : 0;
  sh[t] = v;
  __syncthreads();
  for (int off = 1; off < 1024; off <<= 1) {
    int add = (t >= off) ? sh[t - off] : 0;
    __syncthreads();
    sh[t] += add;
    __syncthreads();
  }
  if (idx < NN) {
    int excl = sh[t] - v + bbase[blockIdx.x];
    rowptr[idx] = excl;
    cursor[idx] = excl;
  }
  if (blockIdx.x == 0 && t == 0) rowptr[NN] = NE;
}

__global__ __launch_bounds__(256) void k_fill_src(const int* __restrict__ src,
                                                  const int* __restrict__ dst,
                                                  int* __restrict__ cursor,
                                                  int* __restrict__ ssrc) {
  int e = blockIdx.x * 256 + threadIdx.x;
  if (e >= NE) return;
  int pos = atomicAdd(&cursor[dst[e]], 1);
  ssrc[pos] = src[e];
}

// ---------------- aggregate: one wave per node ----------------
__global__ __launch_bounds__(256) void k_aggregate(
    const float4* __restrict__ h4, const int* __restrict__ rowptr,
    const int* __restrict__ ssrc, float4* __restrict__ out4) {
  int node = blockIdx.x * 4 + (threadIdx.x >> 6);
  if (node >= NN) return;
  int lane = threadIdx.x & 63;
  int b = rowptr[node], e = rowptr[node + 1];
  float4 acc = make_float4(0.f, 0.f, 0.f, 0.f);
  for (int i = b; i < e; ++i) {
    int s = ssrc[i];
    float4 v = h4[(size_t)s * 64 + lane];
    acc.x += v.x; acc.y += v.y; acc.z += v.z; acc.w += v.w;
  }
  out4[(size_t)node * 64 + lane] = acc;
}

// ---------------- node encode ----------------
__global__ __launch_bounds__(256) void k_node_encode(
    const float* __restrict__ x, const float* __restrict__ w,
    const float* __restrict__ b, float* __restrict__ h) {
  int n = blockIdx.x, d = threadIdx.x;
  __shared__ float xr[20];
  if (d < 20) xr[d] = x[n * 20 + d];
  __syncthreads();
  float s = b[d];
#pragma unroll
  for (int k = 0; k < 20; ++k) s = fmaf(xr[k], w[k * DD + d], s);
  h[(size_t)n * DD + d] = s;
}

__global__ __launch_bounds__(256) void k_vn_init(const float* __restrict__ vnw,
                                                 float* __restrict__ vn) {
  int i = blockIdx.x * 256 + threadIdx.x;
  vn[i] = vnw[i & (DD - 1)];
}

__global__ __launch_bounds__(256) void k_add_vn(float* __restrict__ h,
                                                const float* __restrict__ vn,
                                                const int* __restrict__ batch) {
  int idx = blockIdx.x * 256 + threadIdx.x;
  int n = idx >> 6, c = idx & 63;
  float4 hv = ((float4*)h)[idx];
  float4 v = ((const float4*)vn)[(size_t)batch[n] * 64 + c];
  hv.x += v.x; hv.y += v.y; hv.z += v.z; hv.w += v.w;
  ((float4*)h)[idx] = hv;
}

// ---------------- pooling ----------------
__global__ __launch_bounds__(256) void k_pool(const float* __restrict__ h,
                                              const int* __restrict__ batch,
                                              float* __restrict__ out) {
  const int CH = 128;
  int n0 = blockIdx.x * CH;
  int d = threadIdx.x;
  __shared__ int bs[CH];
  for (int i = threadIdx.x; i < CH; i += 256) {
    int n = n0 + i;
    bs[i] = (n < NN) ? batch[n] : -1;
  }
  __syncthreads();
  int nmax = min(CH, NN - n0);
  float acc = 0.f;
  int cur = bs[0];
  for (int i = 0; i < nmax; ++i) {
    int g = bs[i];
    if (g != cur) {
      atomicAdd(&out[(size_t)cur * DD + d], acc);
      acc = 0.f;
      cur = g;
    }
    acc += h[(size_t)(n0 + i) * DD + d];
  }
  atomicAdd(&out[(size_t)cur * DD + d], acc);
}

// ---------------- MFMA GEMM: 64x256 stripe per block, bf16 inputs fp32 acc -------
// C[m0:m0+64, :] = epi((A [+A2]) @ W + bias); W pre-packed fragment-major bf16.
// One barrier total (after A staging): K-loop is ds_read + global L2 loads + MFMA.
template <bool ADD2, bool BNLEAKY>
__global__ __launch_bounds__(256) void k_gemm_mfma(
    const float* __restrict__ A, const float* __restrict__ A2,
    const unsigned short* __restrict__ Wf, const float* __restrict__ bias,
    const float* __restrict__ bng, const float* __restrict__ bnb,
    const float* __restrict__ bnm, const float* __restrict__ bnv,
    float* __restrict__ C) {
  __shared__ unsigned short As[64][272];  // 544B row stride: 16B aligned, 2-way banks
  int tid = threadIdx.x;
  int m0 = blockIdx.x * 64;
  // stage A (+A2) -> bf16 LDS, coalesced float4 loads
#pragma unroll
  for (int i = 0; i < 16; ++i) {
    int p = i * 256 + tid;          // float4 index in 64x64-float4 tile
    int row = p >> 6, k4 = p & 63;
    int m = m0 + row;
    float4 v = make_float4(0.f, 0.f, 0.f, 0.f);
    if (m < NN) {
      v = *(const float4*)(A + (size_t)m * DD + (k4 << 2));
      if (ADD2) {
        float4 u = *(const float4*)(A2 + (size_t)m * DD + (k4 << 2));
        v.x += u.x; v.y += u.y; v.z += u.z; v.w += u.w;
      }
    }
    *(ushort4*)&As[row][k4 << 2] =
        make_ushort4(f2bf(v.x), f2bf(v.y), f2bf(v.z), f2bf(v.w));
  }
  __syncthreads();

  int wave = tid >> 6, lane = tid & 63;
  int wm = wave & 1;        // m-tile (32 rows)
  int nhalf = wave >> 1;    // 128-col half
  int lrow = lane & 31, lhi = lane >> 5;

  floatx16 acc[4];
#pragma unroll
  for (int j = 0; j < 4; ++j) acc[j] = (floatx16)(0.f);

  const bf16x8* wf = (const bf16x8*)Wf;
  const unsigned short* arow = &As[wm * 32 + lrow][lhi << 3];

#pragma unroll 2
  for (int ks = 0; ks < 16; ++ks) {
    bf16x8 a = *(const bf16x8*)(arow + ks * 16);
#pragma unroll
    for (int j = 0; j < 4; ++j) {
      int nt = nhalf * 4 + j;
      bf16x8 b = wf[((nt * 16 + ks) << 6) + lane];
      acc[j] = __builtin_amdgcn_mfma_f32_32x32x16_bf16(a, b, acc[j], 0, 0, 0);
    }
  }

  // epilogue: C/D layout col=lane&31, row=(reg&3)+8*(reg>>2)+4*(lane>>5)
#pragma unroll
  for (int j = 0; j < 4; ++j) {
    int ncol = nhalf * 128 + j * 32 + lrow;
    float scl, shf;
    float bsv = bias[ncol];
    if (BNLEAKY) {
      float s = bng[ncol] * rsqrtf(bnv[ncol] + BN_EPS);
      scl = s;
      shf = bsv * s + bnb[ncol] - bnm[ncol] * s;
    } else {
      scl = 1.f;
      shf = bsv;
    }
#pragma unroll
    for (int reg = 0; reg < 16; ++reg) {
      int row = (reg & 3) + ((reg >> 2) << 3) + (lhi << 2);
      int m = m0 + wm * 32 + row;
      if (m < NN) {
        float v = acc[j][reg] * scl + shf;
        if (BNLEAKY) v = (v > 0.f) ? v : 0.1f * v;
        else v = fmaxf(v, 0.f);
        C[(size_t)m * DD + ncol] = v;
      }
    }
  }
}

// ---------------- small GEMM, one block per row ----------------
template <int MODE>
__global__ __launch_bounds__(256) void k_gemm_row(
    const float* __restrict__ X, const float* __restrict__ W,
    const float* __restrict__ bias,
    const float* __restrict__ bng, const float* __restrict__ bnb,
    const float* __restrict__ bnm, const float* __restrict__ bnv,
    float* __restrict__ Y, int K, int N) {
  __shared__ float xs[DD];
  int m = blockIdx.x;
  for (int k = threadIdx.x; k < K; k += 256) xs[k] = X[(size_t)m * K + k];
  __syncthreads();
  for (int n = threadIdx.x; n < N; n += 256) {
    float s = bias[n];
    for (int k = 0; k < K; ++k) s = fmaf(xs[k], W[(size_t)k * N + n], s);
    if (MODE == 1) {
      float scl = bng[n] * rsqrtf(bnv[n] + BN_EPS);
      s = s * scl + (bnb[n] - bnm[n] * scl);
    }
    if (MODE <= 1) s = fmaxf(s, 0.f);
    Y[(size_t)m * N + n] = s;
  }
}

extern "C" void kernel_launch(void* const* d_in, const int* in_sizes, int n_in,
                              void* d_out, int out_size, void* d_ws, size_t ws_size,
                              hipStream_t stream) {
  const float* x      = (const float*)d_in[0];
  const int*   ei     = (const int*)d_in[1];
  const int*   batch  = (const int*)d_in[2];
  const float* node_w = (const float*)d_in[3];
  const float* node_b = (const float*)d_in[4];
  const float* vn_w   = (const float*)d_in[5];
  const float* gin_w1 = (const float*)d_in[6];
  const float* gin_b1 = (const float*)d_in[7];
  const float* gin_w2 = (const float*)d_in[8];
  const float* gin_b2 = (const float*)d_in[9];
  const float* bn_g   = (const float*)d_in[10];
  const float* bn_b   = (const float*)d_in[11];
  const float* bn_m   = (const float*)d_in[12];
  const float* bn_v   = (const float*)d_in[13];
  const float* vn_w1  = (const float*)d_in[14];
  const float* vn_b1  = (const float*)d_in[15];
  const float* vbn1g  = (const float*)d_in[16];
  const float* vbn1b  = (const float*)d_in[17];
  const float* vbn1m  = (const float*)d_in[18];
  const float* vbn1v  = (const float*)d_in[19];
  const float* vn_w2  = (const float*)d_in[20];
  const float* vn_b2  = (const float*)d_in[21];
  const float* vbn2g  = (const float*)d_in[22];
  const float* vbn2b  = (const float*)d_in[23];
  const float* vbn2m  = (const float*)d_in[24];
  const float* vbn2v  = (const float*)d_in[25];
  const float* head_w1 = (const float*)d_in[26];
  const float* head_b1 = (const float*)d_in[27];
  const float* head_w2 = (const float*)d_in[28];
  const float* head_b2 = (const float*)d_in[29];
  const float* head_w3 = (const float*)d_in[30];
  const float* head_b3 = (const float*)d_in[31];

  float* ws  = (float*)d_ws;
  float* h   = ws;                       // [NN, DD]
  float* agg = h + (size_t)NN * DD;      // [NN, DD] (GIN hidden in place)
  float* vn  = agg + (size_t)NN * DD;
  float* t0  = vn + (size_t)NG * DD;
  float* t1  = t0 + (size_t)NG * DD;
  float* gh1 = t1 + (size_t)NG * DD;     // [NG,128]
  float* gh2 = gh1 + (size_t)NG * 128;   // [NG,64]
  int* rowptr = (int*)(gh2 + (size_t)NG * 64);  // [NN+1]
  int* cursor = rowptr + NN + 1;                // [NN]
  int* ssrc   = cursor + NN;                    // [NE]
  int* bsum   = ssrc + NE;                      // [98]
  int* bbase  = bsum + 128;                     // [98]
  unsigned short* wf1 = (unsigned short*)(bbase + 128);  // [5*65536]
  unsigned short* wf2 = wf1 + 5 * 65536;                 // [5*65536]

  const int* src = ei;
  const int* dst = ei + NE;

  const int NND4 = NN * DD / 4;
  const int NGD4 = NG * DD / 4;
  const int NB = (NN + 1023) / 1024;  // 98

  // ---- once per launch: weight pack + CSR build ----
  k_pack_w<<<(5 * 65536 + 255) / 256, 256, 0, stream>>>(gin_w1, wf1, 5);
  k_pack_w<<<(5 * 65536 + 255) / 256, 256, 0, stream>>>(gin_w2, wf2, 5);
  k_zeroi<<<(NN + 255) / 256, 256, 0, stream>>>(cursor, NN);
  k_hist<<<(NE + 255) / 256, 256, 0, stream>>>(dst, cursor);
  k_bsum<<<NB, 1024, 0, stream>>>(cursor, bsum);
  k_scanb<<<1, 128, 0, stream>>>(bsum, bbase, NB);
  k_rowptr<<<NB, 1024, 0, stream>>>(cursor, bbase, rowptr, cursor);
  k_fill_src<<<(NE + 255) / 256, 256, 0, stream>>>(src, dst, cursor, ssrc);

  k_node_encode<<<NN, 256, 0, stream>>>(x, node_w, node_b, h);
  k_vn_init<<<NG * DD / 256, 256, 0, stream>>>(vn_w, vn);

  for (int l = 0; l < NL; ++l) {
    k_add_vn<<<NND4 / 256, 256, 0, stream>>>(h, vn, batch);
    k_aggregate<<<(NN + 3) / 4, 256, 0, stream>>>((const float4*)h, rowptr, ssrc,
                                                  (float4*)agg);
    // agg = relu((h + agg) @ W1 + b1)  [in place]
    k_gemm_mfma<true, false><<<(NN + 63) / 64, 256, 0, stream>>>(
        h, agg, wf1 + (size_t)l * 65536, gin_b1 + l * DD,
        nullptr, nullptr, nullptr, nullptr, agg);
    // h = leaky(bn(agg @ W2 + b2))
    k_gemm_mfma<false, true><<<(NN + 63) / 64, 256, 0, stream>>>(
        agg, nullptr, wf2 + (size_t)l * 65536, gin_b2 + l * DD,
        bn_g + l * DD, bn_b + l * DD, bn_m + l * DD, bn_v + l * DD, h);
    if (l < NL - 1) {
      k_copy4<<<(NGD4 + 255) / 256, 256, 0, stream>>>((float4*)t0, (const float4*)vn, NGD4);
      k_pool<<<(NN + 127) / 128, 256, 0, stream>>>(h, batch, t0);
      k_gemm_row<1><<<NG, 256, 0, stream>>>(
          t0, vn_w1 + (size_t)l * DD * DD, vn_b1 + l * DD,
          vbn1g + l * DD, vbn1b + l * DD, vbn1m + l * DD, vbn1v + l * DD,
          t1, DD, DD);
      k_gemm_row<1><<<NG, 256, 0, stream>>>(
          t1, vn_w2 + (size_t)l * DD * DD, vn_b2 + l * DD,
          vbn2g + l * DD, vbn2b + l * DD, vbn2m + l * DD, vbn2v + l * DD,
          vn, DD, DD);
    }
  }
  k_zero4<<<(NGD4 + 255) / 256, 256, 0, stream>>>((float4*)t0, NGD4);
  k_pool<<<(NN + 127) / 128, 256, 0, stream>>>(h, batch, t0);
  k_gemm_row<0><<<NG, 256, 0, stream>>>(
      t0, head_w1, head_b1, nullptr, nullptr, nullptr, nullptr, gh1, DD, 128);
  k_gemm_row<0><<<NG, 256, 0, stream>>>(
      gh1, head_w2, head_b2, nullptr, nullptr, nullptr, nullptr, gh2, 128, 64);
  k_gemm_row<2><<<NG, 256, 0, stream>>>(
      gh2, head_w3, head_b3, nullptr, nullptr, nullptr, nullptr, (float*)d_out, 64, 11);
}

// Round 5
// 1862.876 us; speedup vs baseline: 4.3004x; 1.0438x over previous
//
#include <hip/hip_runtime.h>
#include <hip/hip_bf16.h>

#define NN 100000
#define NE 300000
#define NG 2000
#define DD 256
#define NL 5
#define BN_EPS 1e-5f

typedef __bf16 bf16x8 __attribute__((ext_vector_type(8)));
typedef float floatx16 __attribute__((ext_vector_type(16)));

__device__ inline unsigned short f2bf(float x) {
  unsigned int u = __builtin_bit_cast(unsigned int, x);
  unsigned int r = u + 0x7FFFu + ((u >> 16) & 1u);
  return (unsigned short)(r >> 16);
}
__device__ inline float bf2f(unsigned short u) {
  return __builtin_bit_cast(float, (unsigned int)u << 16);
}
__device__ inline float4 bfu4(ushort4 u) {
  return make_float4(bf2f(u.x), bf2f(u.y), bf2f(u.z), bf2f(u.w));
}

// ---------------- utility ----------------
__global__ __launch_bounds__(256) void k_zero4(float4* __restrict__ p, int n4) {
  int i = blockIdx.x * 256 + threadIdx.x;
  if (i < n4) p[i] = make_float4(0.f, 0.f, 0.f, 0.f);
}
__global__ __launch_bounds__(256) void k_copy4(float4* __restrict__ d,
                                               const float4* __restrict__ s, int n4) {
  int i = blockIdx.x * 256 + threadIdx.x;
  if (i < n4) d[i] = s[i];
}
__global__ __launch_bounds__(256) void k_zeroi(int* __restrict__ p, int n) {
  int i = blockIdx.x * 256 + threadIdx.x;
  if (i < n) p[i] = 0;
}
__global__ __launch_bounds__(256) void k_f2bf(const float* __restrict__ s,
                                              unsigned short* __restrict__ d, int n) {
  int i = blockIdx.x * 256 + threadIdx.x;
  if (i < n) d[i] = f2bf(s[i]);
}

// ---------------- weight pack: W[k][n] fp32 -> fragment-major bf16 ----------------
// Wf flat idx = ((nt*16 + ks)*64 + lane)*8 + j ; n = nt*32+(lane&31), k = ks*16+(lane>>5)*8+j
__global__ __launch_bounds__(256) void k_pack_w(const float* __restrict__ W,
                                                unsigned short* __restrict__ Wf,
                                                int nmat) {
  int idx = blockIdx.x * 256 + threadIdx.x;
  if (idx >= nmat * 65536) return;
  int m = idx >> 16, r = idx & 65535;
  int j = r & 7, lane = (r >> 3) & 63, ks = (r >> 9) & 15, nt = r >> 13;
  int n = nt * 32 + (lane & 31);
  int k = ks * 16 + ((lane >> 5) << 3) + j;
  Wf[idx] = f2bf(W[(size_t)m * 65536 + k * 256 + n]);
}

// ---------------- CSR build ----------------
__global__ __launch_bounds__(256) void k_hist(const int* __restrict__ dst,
                                              int* __restrict__ cnt) {
  int e = blockIdx.x * 256 + threadIdx.x;
  if (e < NE) atomicAdd(&cnt[dst[e]], 1);
}

__global__ __launch_bounds__(1024) void k_bsum(const int* __restrict__ cnt,
                                               int* __restrict__ bsum) {
  __shared__ int sh[1024];
  int t = threadIdx.x, idx = blockIdx.x * 1024 + t;
  sh[t] = (idx < NN) ? cnt[idx] : 0;
  __syncthreads();
  for (int off = 512; off > 0; off >>= 1) {
    if (t < off) sh[t] += sh[t + off];
    __syncthreads();
  }
  if (t == 0) bsum[blockIdx.x] = sh[0];
}

__global__ __launch_bounds__(128) void k_scanb(const int* __restrict__ bsum,
                                               int* __restrict__ bbase, int nb) {
  __shared__ int sh[128];
  int t = threadIdx.x;
  sh[t] = (t < nb) ? bsum[t] : 0;
  __syncthreads();
  if (t == 0) {
    int run = 0;
    for (int i = 0; i < nb; ++i) { int v = sh[i]; sh[i] = run; run += v; }
  }
  __syncthreads();
  if (t < nb) bbase[t] = sh[t];
}

__global__ __launch_bounds__(1024) void k_rowptr(const int* __restrict__ cnt,
                                                 const int* __restrict__ bbase,
                                                 int* __restrict__ rowptr,
                                                 int* __restrict__ cursor) {
  __shared__ int sh[1024];
  int t = threadIdx.x, idx = blockIdx.x * 1024 + t;
  int v = (idx < NN) ? cnt[idx] : 0;
  sh[t] = v;
  __syncthreads();
  for (int off = 1; off < 1024; off <<= 1) {
    int add = (t >= off) ? sh[t - off] : 0;
    __syncthreads();
    sh[t] += add;
    __syncthreads();
  }
  if (idx < NN) {
    int excl = sh[t] - v + bbase[blockIdx.x];
    rowptr[idx] = excl;
    cursor[idx] = excl;
  }
  if (blockIdx.x == 0 && t == 0) rowptr[NN] = NE;
}

__global__ __launch_bounds__(256) void k_fill_src(const int* __restrict__ src,
                                                  const int* __restrict__ dst,
                                                  int* __restrict__ cursor,
                                                  int* __restrict__ ssrc) {
  int e = blockIdx.x * 256 + threadIdx.x;
  if (e >= NE) return;
  int pos = atomicAdd(&cursor[dst[e]], 1);
  ssrc[pos] = src[e];
}

// ---------------- fused aggregate: z[n] = h[n]+vn[b[n]] + sum_src (h[src]+vn[b[src]]) ----
__global__ __launch_bounds__(256) void k_aggregate_vn(
    const unsigned short* __restrict__ h16, const unsigned short* __restrict__ vnb,
    const int* __restrict__ batch, const int* __restrict__ rowptr,
    const int* __restrict__ ssrc, unsigned short* __restrict__ z16) {
  int node = blockIdx.x * 4 + (threadIdx.x >> 6);
  if (node >= NN) return;
  int lane = threadIdx.x & 63;
  int c4 = lane << 2;
  ushort4 hv = *(const ushort4*)(h16 + (size_t)node * DD + c4);
  ushort4 vv = *(const ushort4*)(vnb + (size_t)batch[node] * DD + c4);
  float4 a = bfu4(hv), b4 = bfu4(vv);
  float4 acc = make_float4(a.x + b4.x, a.y + b4.y, a.z + b4.z, a.w + b4.w);
  int b = rowptr[node], e = rowptr[node + 1];
  for (int i = b; i < e; ++i) {
    int s = ssrc[i];
    int g = batch[s];
    float4 u = bfu4(*(const ushort4*)(h16 + (size_t)s * DD + c4));
    float4 w = bfu4(*(const ushort4*)(vnb + (size_t)g * DD + c4));
    acc.x += u.x + w.x; acc.y += u.y + w.y; acc.z += u.z + w.z; acc.w += u.w + w.w;
  }
  *(ushort4*)(z16 + (size_t)node * DD + c4) =
      make_ushort4(f2bf(acc.x), f2bf(acc.y), f2bf(acc.z), f2bf(acc.w));
}

// ---------------- node encode: h = x @ node_w + node_b -> bf16 (4 nodes/block) ------
__global__ __launch_bounds__(256) void k_node_encode(
    const float* __restrict__ x, const float* __restrict__ w,
    const float* __restrict__ b, unsigned short* __restrict__ h16) {
  __shared__ float xr[4][20];
  int n0 = blockIdx.x * 4;
  int tid = threadIdx.x;
  if (tid < 80) xr[tid / 20][tid % 20] = x[(size_t)(n0 + tid / 20) * 20 + tid % 20];
  __syncthreads();
  int ln = tid >> 6, c4 = (tid & 63) << 2;
  int n = n0 + ln;
  float s0 = b[c4], s1 = b[c4 + 1], s2 = b[c4 + 2], s3 = b[c4 + 3];
#pragma unroll
  for (int k = 0; k < 20; ++k) {
    float xv = xr[ln][k];
    const float* wr = w + k * DD + c4;
    s0 = fmaf(xv, wr[0], s0);
    s1 = fmaf(xv, wr[1], s1);
    s2 = fmaf(xv, wr[2], s2);
    s3 = fmaf(xv, wr[3], s3);
  }
  *(ushort4*)(h16 + (size_t)n * DD + c4) =
      make_ushort4(f2bf(s0), f2bf(s1), f2bf(s2), f2bf(s3));
}

__global__ __launch_bounds__(256) void k_vn_init(const float* __restrict__ vnw,
                                                 float* __restrict__ vn) {
  int i = blockIdx.x * 256 + threadIdx.x;
  vn[i] = vnw[i & (DD - 1)];
}

// ---------------- pooling (bf16 input): out[batch[n]] += h[n] ----------------
__global__ __launch_bounds__(256) void k_pool(const unsigned short* __restrict__ h16,
                                              const int* __restrict__ batch,
                                              float* __restrict__ out) {
  const int CH = 128;
  int n0 = blockIdx.x * CH;
  int d = threadIdx.x;
  __shared__ int bs[CH];
  for (int i = threadIdx.x; i < CH; i += 256) {
    int n = n0 + i;
    bs[i] = (n < NN) ? batch[n] : -1;
  }
  __syncthreads();
  int nmax = min(CH, NN - n0);
  float acc = 0.f;
  int cur = bs[0];
  for (int i = 0; i < nmax; ++i) {
    int g = bs[i];
    if (g != cur) {
      atomicAdd(&out[(size_t)cur * DD + d], acc);
      acc = 0.f;
      cur = g;
    }
    acc += bf2f(h16[(size_t)(n0 + i) * DD + d]);
  }
  atomicAdd(&out[(size_t)cur * DD + d], acc);
}

// ---------------- MFMA GEMM: bf16 A [NN,256] x packed bf16 W -> bf16 C ----------------
// As fragment-contiguous: [wm][ks][lhi][lrow][8]; conflict-free b128 both ways.
template <bool BNLEAKY>
__global__ __launch_bounds__(256) void k_gemm_mfma(
    const unsigned short* __restrict__ A16, const unsigned short* __restrict__ Wf,
    const float* __restrict__ bias,
    const float* __restrict__ bng, const float* __restrict__ bnb,
    const float* __restrict__ bnm, const float* __restrict__ bnv,
    unsigned short* __restrict__ C16) {
  __shared__ unsigned short As[2][16][2][32][8];  // 32 KB
  int tid = threadIdx.x;
  int m0 = blockIdx.x * 64;
#pragma unroll
  for (int i = 0; i < 8; ++i) {
    int q = i * 256 + tid;
    int lr = q & 31, lh = (q >> 5) & 1, ks = (q >> 6) & 15, wm = q >> 10;
    int m = m0 + wm * 32 + lr;
    uint4 v = make_uint4(0u, 0u, 0u, 0u);
    if (m < NN) v = *(const uint4*)(A16 + (size_t)m * DD + ks * 16 + lh * 8);
    *(uint4*)&As[wm][ks][lh][lr][0] = v;
  }
  __syncthreads();

  int wave = tid >> 6, lane = tid & 63;
  int wm = wave & 1, nhalf = wave >> 1;
  int lrow = lane & 31, lhi = lane >> 5;

  floatx16 acc[4];
#pragma unroll
  for (int j = 0; j < 4; ++j) acc[j] = (floatx16)(0.f);

  const bf16x8* wf = (const bf16x8*)Wf;
#pragma unroll
  for (int ks = 0; ks < 16; ++ks) {
    bf16x8 a = *(const bf16x8*)&As[wm][ks][lhi][lrow][0];
#pragma unroll
    for (int j = 0; j < 4; ++j) {
      int nt = nhalf * 4 + j;
      bf16x8 b = wf[((nt * 16 + ks) << 6) + lane];
      acc[j] = __builtin_amdgcn_mfma_f32_32x32x16_bf16(a, b, acc[j], 0, 0, 0);
    }
  }

  // epilogue: col=lane&31, row=(reg&3)+8*(reg>>2)+4*(lane>>5)
#pragma unroll
  for (int j = 0; j < 4; ++j) {
    int ncol = nhalf * 128 + j * 32 + lrow;
    float scl, shf;
    float bsv = bias[ncol];
    if (BNLEAKY) {
      float s = bng[ncol] * rsqrtf(bnv[ncol] + BN_EPS);
      scl = s;
      shf = bsv * s + bnb[ncol] - bnm[ncol] * s;
    } else {
      scl = 1.f;
      shf = bsv;
    }
#pragma unroll
    for (int reg = 0; reg < 16; ++reg) {
      int row = (reg & 3) + ((reg >> 2) << 3) + (lhi << 2);
      int m = m0 + wm * 32 + row;
      if (m < NN) {
        float v = acc[j][reg] * scl + shf;
        if (BNLEAKY) v = (v > 0.f) ? v : 0.1f * v;
        else v = fmaxf(v, 0.f);
        C16[(size_t)m * DD + ncol] = f2bf(v);
      }
    }
  }
}

// ---------------- small GEMM, 8 rows/block, fp32 exact ----------------
// MODE 0: bias+relu; 1: bias+bn+relu; 2: bias only
template <int MODE, int K>
__global__ __launch_bounds__(256) void k_gemm_row8(
    const float* __restrict__ X, const float* __restrict__ W,
    const float* __restrict__ bias,
    const float* __restrict__ bng, const float* __restrict__ bnb,
    const float* __restrict__ bnm, const float* __restrict__ bnv,
    float* __restrict__ Y, int N) {
  __shared__ float xs[8][K];
  int m8 = blockIdx.x * 8;
  for (int idx = threadIdx.x; idx < 8 * K; idx += 256) {
    int r = idx / K, k = idx - r * K;
    xs[r][k] = X[(size_t)(m8 + r) * K + k];
  }
  __syncthreads();
  for (int n = threadIdx.x; n < N; n += 256) {
    float bz = bias[n];
    float s[8];
#pragma unroll
    for (int r = 0; r < 8; ++r) s[r] = bz;
    for (int k = 0; k < K; ++k) {
      float w = W[(size_t)k * N + n];
#pragma unroll
      for (int r = 0; r < 8; ++r) s[r] = fmaf(xs[r][k], w, s[r]);
    }
    float scl = 1.f, shf = 0.f;
    if (MODE == 1) {
      scl = bng[n] * rsqrtf(bnv[n] + BN_EPS);
      shf = bnb[n] - bnm[n] * scl;
    }
#pragma unroll
    for (int r = 0; r < 8; ++r) {
      float v = s[r];
      if (MODE == 1) v = v * scl + shf;
      if (MODE <= 1) v = fmaxf(v, 0.f);
      Y[(size_t)(m8 + r) * N + n] = v;
    }
  }
}

extern "C" void kernel_launch(void* const* d_in, const int* in_sizes, int n_in,
                              void* d_out, int out_size, void* d_ws, size_t ws_size,
                              hipStream_t stream) {
  const float* x      = (const float*)d_in[0];
  const int*   ei     = (const int*)d_in[1];
  const int*   batch  = (const int*)d_in[2];
  const float* node_w = (const float*)d_in[3];
  const float* node_b = (const float*)d_in[4];
  const float* vn_w   = (const float*)d_in[5];
  const float* gin_w1 = (const float*)d_in[6];
  const float* gin_b1 = (const float*)d_in[7];
  const float* gin_w2 = (const float*)d_in[8];
  const float* gin_b2 = (const float*)d_in[9];
  const float* bn_g   = (const float*)d_in[10];
  const float* bn_b   = (const float*)d_in[11];
  const float* bn_m   = (const float*)d_in[12];
  const float* bn_v   = (const float*)d_in[13];
  const float* vn_w1  = (const float*)d_in[14];
  const float* vn_b1  = (const float*)d_in[15];
  const float* vbn1g  = (const float*)d_in[16];
  const float* vbn1b  = (const float*)d_in[17];
  const float* vbn1m  = (const float*)d_in[18];
  const float* vbn1v  = (const float*)d_in[19];
  const float* vn_w2  = (const float*)d_in[20];
  const float* vn_b2  = (const float*)d_in[21];
  const float* vbn2g  = (const float*)d_in[22];
  const float* vbn2b  = (const float*)d_in[23];
  const float* vbn2m  = (const float*)d_in[24];
  const float* vbn2v  = (const float*)d_in[25];
  const float* head_w1 = (const float*)d_in[26];
  const float* head_b1 = (const float*)d_in[27];
  const float* head_w2 = (const float*)d_in[28];
  const float* head_b2 = (const float*)d_in[29];
  const float* head_w3 = (const float*)d_in[30];
  const float* head_b3 = (const float*)d_in[31];

  // ---- workspace layout (~165 MB) ----
  unsigned short* h16   = (unsigned short*)d_ws;          // [NN*DD]
  unsigned short* z16   = h16 + (size_t)NN * DD;          // [NN*DD]
  unsigned short* hid16 = z16 + (size_t)NN * DD;          // [NN*DD]
  unsigned short* vnb   = hid16 + (size_t)NN * DD;        // [NG*DD] bf16 vn
  unsigned short* wf1   = vnb + (size_t)NG * DD;          // [5*65536]
  unsigned short* wf2   = wf1 + 5 * 65536;                // [5*65536]
  float* vn  = (float*)(wf2 + 5 * 65536);                 // [NG*DD]
  float* t0  = vn + (size_t)NG * DD;                      // [NG*DD]
  float* t1  = t0 + (size_t)NG * DD;                      // [NG*DD]
  float* gh1 = t1 + (size_t)NG * DD;                      // [NG*128]
  float* gh2 = gh1 + (size_t)NG * 128;                    // [NG*64]
  int* rowptr = (int*)(gh2 + (size_t)NG * 64);            // [NN+1]
  int* cursor = rowptr + NN + 1;                          // [NN]
  int* ssrc   = cursor + NN;                              // [NE]
  int* bsum   = ssrc + NE;                                // [128]
  int* bbase  = bsum + 128;                               // [128]

  const int* src = ei;
  const int* dst = ei + NE;

  const int NGD4 = NG * DD / 4;
  const int NB = (NN + 1023) / 1024;  // 98

  // ---- once per launch: weight pack + CSR ----
  k_pack_w<<<(5 * 65536 + 255) / 256, 256, 0, stream>>>(gin_w1, wf1, 5);
  k_pack_w<<<(5 * 65536 + 255) / 256, 256, 0, stream>>>(gin_w2, wf2, 5);
  k_zeroi<<<(NN + 255) / 256, 256, 0, stream>>>(cursor, NN);
  k_hist<<<(NE + 255) / 256, 256, 0, stream>>>(dst, cursor);
  k_bsum<<<NB, 1024, 0, stream>>>(cursor, bsum);
  k_scanb<<<1, 128, 0, stream>>>(bsum, bbase, NB);
  k_rowptr<<<NB, 1024, 0, stream>>>(cursor, bbase, rowptr, cursor);
  k_fill_src<<<(NE + 255) / 256, 256, 0, stream>>>(src, dst, cursor, ssrc);

  k_node_encode<<<NN / 4, 256, 0, stream>>>(x, node_w, node_b, h16);
  k_vn_init<<<NG * DD / 256, 256, 0, stream>>>(vn_w, vn);

  for (int l = 0; l < NL; ++l) {
    k_f2bf<<<(NG * DD + 255) / 256, 256, 0, stream>>>(vn, vnb, NG * DD);
    k_aggregate_vn<<<(NN + 3) / 4, 256, 0, stream>>>(h16, vnb, batch, rowptr, ssrc, z16);
    // hid = relu(z @ W1 + b1)
    k_gemm_mfma<false><<<(NN + 63) / 64, 256, 0, stream>>>(
        z16, wf1 + (size_t)l * 65536, gin_b1 + l * DD,
        nullptr, nullptr, nullptr, nullptr, hid16);
    // h = leaky(bn(hid @ W2 + b2))
    k_gemm_mfma<true><<<(NN + 63) / 64, 256, 0, stream>>>(
        hid16, wf2 + (size_t)l * 65536, gin_b2 + l * DD,
        bn_g + l * DD, bn_b + l * DD, bn_m + l * DD, bn_v + l * DD, h16);
    if (l < NL - 1) {
      k_copy4<<<(NGD4 + 255) / 256, 256, 0, stream>>>((float4*)t0, (const float4*)vn, NGD4);
      k_pool<<<(NN + 127) / 128, 256, 0, stream>>>(h16, batch, t0);
      k_gemm_row8<1, DD><<<NG / 8, 256, 0, stream>>>(
          t0, vn_w1 + (size_t)l * DD * DD, vn_b1 + l * DD,
          vbn1g + l * DD, vbn1b + l * DD, vbn1m + l * DD, vbn1v + l * DD, t1, DD);
      k_gemm_row8<1, DD><<<NG / 8, 256, 0, stream>>>(
          t1, vn_w2 + (size_t)l * DD * DD, vn_b2 + l * DD,
          vbn2g + l * DD, vbn2b + l * DD, vbn2m + l * DD, vbn2v + l * DD, vn, DD);
    }
  }
  k_zero4<<<(NGD4 + 255) / 256, 256, 0, stream>>>((float4*)t0, NGD4);
  k_pool<<<(NN + 127) / 128, 256, 0, stream>>>(h16, batch, t0);
  k_gemm_row8<0, 256><<<NG / 8, 256, 0, stream>>>(
      t0, head_w1, head_b1, nullptr, nullptr, nullptr, nullptr, gh1, 128);
  k_gemm_row8<0, 128><<<NG / 8, 256, 0, stream>>>(
      gh1, head_w2, head_b2, nullptr, nullptr, nullptr, nullptr, gh2, 64);
  k_gemm_row8<2, 64><<<NG / 8, 256, 0, stream>>>(
      gh2, head_w3, head_b3, nullptr, nullptr, nullptr, nullptr, (float*)d_out, 11);
}

// Round 6
// 1279.750 us; speedup vs baseline: 6.2599x; 1.4557x over previous
//
#include <hip/hip_runtime.h>
#include <hip/hip_bf16.h>

#define NN 100000
#define NE 300000
#define NG 2000
#define DD 256
#define NL 5
#define BN_EPS 1e-5f

typedef __bf16 bf16x8 __attribute__((ext_vector_type(8)));
typedef float floatx16 __attribute__((ext_vector_type(16)));

__device__ inline unsigned short f2bf(float x) {
  unsigned int u = __builtin_bit_cast(unsigned int, x);
  unsigned int r = u + 0x7FFFu + ((u >> 16) & 1u);
  return (unsigned short)(r >> 16);
}
__device__ inline float bf2f(unsigned short u) {
  return __builtin_bit_cast(float, (unsigned int)u << 16);
}
__device__ inline float4 bfu4(ushort4 u) {
  return make_float4(bf2f(u.x), bf2f(u.y), bf2f(u.z), bf2f(u.w));
}

// ---------------- utility ----------------
__global__ __launch_bounds__(256) void k_zero4(float4* __restrict__ p, int n4) {
  int i = blockIdx.x * 256 + threadIdx.x;
  if (i < n4) p[i] = make_float4(0.f, 0.f, 0.f, 0.f);
}
__global__ __launch_bounds__(256) void k_zeroi(int* __restrict__ p, int n) {
  int i = blockIdx.x * 256 + threadIdx.x;
  if (i < n) p[i] = 0;
}
__global__ __launch_bounds__(256) void k_f2bf(const float* __restrict__ s,
                                              unsigned short* __restrict__ d, int n) {
  int i = blockIdx.x * 256 + threadIdx.x;
  if (i < n) d[i] = f2bf(s[i]);
}
// t0[i] = float(vnb[i])  (init pool accumulator with current VN state)
__global__ __launch_bounds__(256) void k_bf2f(const unsigned short* __restrict__ s,
                                              float* __restrict__ d, int n) {
  int i = blockIdx.x * 256 + threadIdx.x;
  if (i < n) d[i] = bf2f(s[i]);
}

// ---------------- weight pack: W[k][n] fp32 (256x256) -> fragment-major bf16 -------
__global__ __launch_bounds__(256) void k_pack_w(const float* __restrict__ W,
                                                unsigned short* __restrict__ Wf,
                                                int nmat) {
  int idx = blockIdx.x * 256 + threadIdx.x;
  if (idx >= nmat * 65536) return;
  int m = idx >> 16, r = idx & 65535;
  int j = r & 7, lane = (r >> 3) & 63, ks = (r >> 9) & 15, nt = r >> 13;
  int n = nt * 32 + (lane & 31);
  int k = ks * 16 + ((lane >> 5) << 3) + j;
  Wf[idx] = f2bf(W[(size_t)m * 65536 + k * 256 + n]);
}

// ---------------- CSR build ----------------
__global__ __launch_bounds__(256) void k_hist(const int* __restrict__ dst,
                                              int* __restrict__ cnt) {
  int e = blockIdx.x * 256 + threadIdx.x;
  if (e < NE) atomicAdd(&cnt[dst[e]], 1);
}

__global__ __launch_bounds__(1024) void k_bsum(const int* __restrict__ cnt,
                                               int* __restrict__ bsum) {
  __shared__ int sh[1024];
  int t = threadIdx.x, idx = blockIdx.x * 1024 + t;
  sh[t] = (idx < NN) ? cnt[idx] : 0;
  __syncthreads();
  for (int off = 512; off > 0; off >>= 1) {
    if (t < off) sh[t] += sh[t + off];
    __syncthreads();
  }
  if (t == 0) bsum[blockIdx.x] = sh[0];
}

__global__ __launch_bounds__(128) void k_scanb(const int* __restrict__ bsum,
                                               int* __restrict__ bbase, int nb) {
  __shared__ int sh[128];
  int t = threadIdx.x;
  sh[t] = (t < nb) ? bsum[t] : 0;
  __syncthreads();
  if (t == 0) {
    int run = 0;
    for (int i = 0; i < nb; ++i) { int v = sh[i]; sh[i] = run; run += v; }
  }
  __syncthreads();
  if (t < nb) bbase[t] = sh[t];
}

__global__ __launch_bounds__(1024) void k_rowptr(const int* __restrict__ cnt,
                                                 const int* __restrict__ bbase,
                                                 int* __restrict__ rowptr,
                                                 int* __restrict__ cursor) {
  __shared__ int sh[1024];
  int t = threadIdx.x, idx = blockIdx.x * 1024 + t;
  int v = (idx < NN) ? cnt[idx] : 0;
  sh[t] = v;
  __syncthreads();
  for (int off = 1; off < 1024; off <<= 1) {
    int add = (t >= off) ? sh[t - off] : 0;
    __syncthreads();
    sh[t] += add;
    __syncthreads();
  }
  if (idx < NN) {
    int excl = sh[t] - v + bbase[blockIdx.x];
    rowptr[idx] = excl;
    cursor[idx] = excl;
  }
  if (blockIdx.x == 0 && t == 0) rowptr[NN] = NE;
}

__global__ __launch_bounds__(256) void k_fill_src(const int* __restrict__ src,
                                                  const int* __restrict__ dst,
                                                  int* __restrict__ cursor,
                                                  int* __restrict__ ssrc) {
  int e = blockIdx.x * 256 + threadIdx.x;
  if (e >= NE) return;
  int pos = atomicAdd(&cursor[dst[e]], 1);
  ssrc[pos] = src[e];
}

// ---------------- fused aggregate: z[n] = h[n]+vn[b[n]] + sum_src (h[src]+vn[b[src]]) ----
__global__ __launch_bounds__(256) void k_aggregate_vn(
    const unsigned short* __restrict__ h16, const unsigned short* __restrict__ vnb,
    const int* __restrict__ batch, const int* __restrict__ rowptr,
    const int* __restrict__ ssrc, unsigned short* __restrict__ z16) {
  int node = blockIdx.x * 4 + (threadIdx.x >> 6);
  if (node >= NN) return;
  int lane = threadIdx.x & 63;
  int c4 = lane << 2;
  ushort4 hv = *(const ushort4*)(h16 + (size_t)node * DD + c4);
  ushort4 vv = *(const ushort4*)(vnb + (size_t)batch[node] * DD + c4);
  float4 a = bfu4(hv), b4 = bfu4(vv);
  float4 acc = make_float4(a.x + b4.x, a.y + b4.y, a.z + b4.z, a.w + b4.w);
  int b = rowptr[node], e = rowptr[node + 1];
  for (int i = b; i < e; ++i) {
    int s = ssrc[i];
    int g = batch[s];
    float4 u = bfu4(*(const ushort4*)(h16 + (size_t)s * DD + c4));
    float4 w = bfu4(*(const ushort4*)(vnb + (size_t)g * DD + c4));
    acc.x += u.x + w.x; acc.y += u.y + w.y; acc.z += u.z + w.z; acc.w += u.w + w.w;
  }
  *(ushort4*)(z16 + (size_t)node * DD + c4) =
      make_ushort4(f2bf(acc.x), f2bf(acc.y), f2bf(acc.z), f2bf(acc.w));
}

// ---------------- node encode -> bf16 (4 nodes/block) ----------------
__global__ __launch_bounds__(256) void k_node_encode(
    const float* __restrict__ x, const float* __restrict__ w,
    const float* __restrict__ b, unsigned short* __restrict__ h16) {
  __shared__ float xr[4][20];
  int n0 = blockIdx.x * 4;
  int tid = threadIdx.x;
  if (tid < 80) xr[tid / 20][tid % 20] = x[(size_t)(n0 + tid / 20) * 20 + tid % 20];
  __syncthreads();
  int ln = tid >> 6, c4 = (tid & 63) << 2;
  int n = n0 + ln;
  float s0 = b[c4], s1 = b[c4 + 1], s2 = b[c4 + 2], s3 = b[c4 + 3];
#pragma unroll
  for (int k = 0; k < 20; ++k) {
    float xv = xr[ln][k];
    const float* wr = w + k * DD + c4;
    s0 = fmaf(xv, wr[0], s0);
    s1 = fmaf(xv, wr[1], s1);
    s2 = fmaf(xv, wr[2], s2);
    s3 = fmaf(xv, wr[3], s3);
  }
  *(ushort4*)(h16 + (size_t)n * DD + c4) =
      make_ushort4(f2bf(s0), f2bf(s1), f2bf(s2), f2bf(s3));
}

__global__ __launch_bounds__(256) void k_vn_init(const float* __restrict__ vnw,
                                                 unsigned short* __restrict__ vnb) {
  int i = blockIdx.x * 256 + threadIdx.x;
  vnb[i] = f2bf(vnw[i & (DD - 1)]);
}

// ---------------- pooling (bf16 input): out[batch[n]] += h[n] ----------------
__global__ __launch_bounds__(256) void k_pool(const unsigned short* __restrict__ h16,
                                              const int* __restrict__ batch,
                                              float* __restrict__ out) {
  const int CH = 128;
  int n0 = blockIdx.x * CH;
  int d = threadIdx.x;
  __shared__ int bs[CH];
  for (int i = threadIdx.x; i < CH; i += 256) {
    int n = n0 + i;
    bs[i] = (n < NN) ? batch[n] : -1;
  }
  __syncthreads();
  int nmax = min(CH, NN - n0);
  float acc = 0.f;
  int cur = bs[0];
  for (int i = 0; i < nmax; ++i) {
    int g = bs[i];
    if (g != cur) {
      atomicAdd(&out[(size_t)cur * DD + d], acc);
      acc = 0.f;
      cur = g;
    }
    acc += bf2f(h16[(size_t)(n0 + i) * DD + d]);
  }
  atomicAdd(&out[(size_t)cur * DD + d], acc);
}

// ---------------- MFMA GEMM: bf16 A [M,256] x packed bf16 W [256,256] -> bf16 C ------
// EPI: 0 = relu(v+bias); 1 = leaky0.1(bn(v+bias)); 2 = relu(bn(v+bias))
template <int EPI>
__global__ __launch_bounds__(256) void k_gemm_mfma(
    const unsigned short* __restrict__ A16, const unsigned short* __restrict__ Wf,
    const float* __restrict__ bias,
    const float* __restrict__ bng, const float* __restrict__ bnb,
    const float* __restrict__ bnm, const float* __restrict__ bnv,
    unsigned short* __restrict__ C16, int Mtot) {
  __shared__ unsigned short As[2][16][2][32][8];  // 32 KB
  int tid = threadIdx.x;
  int m0 = blockIdx.x * 64;
#pragma unroll
  for (int i = 0; i < 8; ++i) {
    int q = i * 256 + tid;
    int lr = q & 31, lh = (q >> 5) & 1, ks = (q >> 6) & 15, wm = q >> 10;
    int m = m0 + wm * 32 + lr;
    uint4 v = make_uint4(0u, 0u, 0u, 0u);
    if (m < Mtot) v = *(const uint4*)(A16 + (size_t)m * DD + ks * 16 + lh * 8);
    *(uint4*)&As[wm][ks][lh][lr][0] = v;
  }
  __syncthreads();

  int wave = tid >> 6, lane = tid & 63;
  int wm = wave & 1, nhalf = wave >> 1;
  int lrow = lane & 31, lhi = lane >> 5;

  floatx16 acc[4];
#pragma unroll
  for (int j = 0; j < 4; ++j) acc[j] = (floatx16)(0.f);

  const bf16x8* wf = (const bf16x8*)Wf;
#pragma unroll
  for (int ks = 0; ks < 16; ++ks) {
    bf16x8 a = *(const bf16x8*)&As[wm][ks][lhi][lrow][0];
#pragma unroll
    for (int j = 0; j < 4; ++j) {
      int nt = nhalf * 4 + j;
      bf16x8 b = wf[((nt * 16 + ks) << 6) + lane];
      acc[j] = __builtin_amdgcn_mfma_f32_32x32x16_bf16(a, b, acc[j], 0, 0, 0);
    }
  }

  // epilogue: col=lane&31, row=(reg&3)+8*(reg>>2)+4*(lane>>5)
#pragma unroll
  for (int j = 0; j < 4; ++j) {
    int ncol = nhalf * 128 + j * 32 + lrow;
    float scl, shf;
    float bsv = bias[ncol];
    if (EPI >= 1) {
      float s = bng[ncol] * rsqrtf(bnv[ncol] + BN_EPS);
      scl = s;
      shf = bsv * s + bnb[ncol] - bnm[ncol] * s;
    } else {
      scl = 1.f;
      shf = bsv;
    }
#pragma unroll
    for (int reg = 0; reg < 16; ++reg) {
      int row = (reg & 3) + ((reg >> 2) << 3) + (lhi << 2);
      int m = m0 + wm * 32 + row;
      if (m < Mtot) {
        float v = acc[j][reg] * scl + shf;
        if (EPI == 1) v = (v > 0.f) ? v : 0.1f * v;
        else v = fmaxf(v, 0.f);
        C16[(size_t)m * DD + ncol] = f2bf(v);
      }
    }
  }
}

// ---------------- fused head: out = relu(relu(g@W1+b1)@W2+b2)@W3+b3, all fp32 -------
// one block per 32 rows of g [NG,256]
__global__ __launch_bounds__(256) void k_head(
    const float* __restrict__ X,
    const float* __restrict__ w1, const float* __restrict__ b1,
    const float* __restrict__ w2, const float* __restrict__ b2,
    const float* __restrict__ w3, const float* __restrict__ b3,
    float* __restrict__ out) {
  __shared__ float Xs[32][260];
  __shared__ float Ws[8192];     // W1 64x128 chunk / W2 128x64
  __shared__ float H1[32][132];
  __shared__ float H2[32][68];
  __shared__ float W3s[64][12];
  int tid = threadIdx.x;
  int m0 = blockIdx.x * 32;
  // stage X (32x256) + W3
#pragma unroll
  for (int i = 0; i < 8; ++i) {
    int p = i * 256 + tid;
    int r = p >> 6, c4 = (p & 63) << 2;
    float4 v = make_float4(0.f, 0.f, 0.f, 0.f);
    if (m0 + r < NG) v = *(const float4*)(X + (size_t)(m0 + r) * 256 + c4);
    *(float4*)&Xs[r][c4] = v;
  }
  for (int p = tid; p < 704; p += 256) W3s[p / 11][p % 11] = w3[p];

  // ---- layer1: [32,256]@[256,128], thread = 4 rows x 4 cols ----
  int r0 = (tid >> 5) << 2;
  int c0 = (tid & 31) << 2;
  float a1[4][4] = {};
  for (int k0 = 0; k0 < 256; k0 += 64) {
    __syncthreads();
#pragma unroll
    for (int i = 0; i < 8; ++i) {
      int p = i * 256 + tid;
      int r = p >> 5, c4 = (p & 31) << 2;
      *(float4*)&Ws[r * 128 + c4] = *(const float4*)(w1 + (size_t)(k0 + r) * 128 + c4);
    }
    __syncthreads();
#pragma unroll 4
    for (int k = 0; k < 64; ++k) {
      float4 wv = *(float4*)&Ws[k * 128 + c0];
      float xv[4];
#pragma unroll
      for (int i = 0; i < 4; ++i) xv[i] = Xs[r0 + i][k0 + k];
#pragma unroll
      for (int i = 0; i < 4; ++i) {
        a1[i][0] = fmaf(xv[i], wv.x, a1[i][0]);
        a1[i][1] = fmaf(xv[i], wv.y, a1[i][1]);
        a1[i][2] = fmaf(xv[i], wv.z, a1[i][2]);
        a1[i][3] = fmaf(xv[i], wv.w, a1[i][3]);
      }
    }
  }
#pragma unroll
  for (int i = 0; i < 4; ++i) {
    float4 o;
    o.x = fmaxf(a1[i][0] + b1[c0 + 0], 0.f);
    o.y = fmaxf(a1[i][1] + b1[c0 + 1], 0.f);
    o.z = fmaxf(a1[i][2] + b1[c0 + 2], 0.f);
    o.w = fmaxf(a1[i][3] + b1[c0 + 3], 0.f);
    *(float4*)&H1[r0 + i][c0] = o;
  }
  __syncthreads();
  // ---- layer2: [32,128]@[128,64], thread = 2 rows x 4 cols ----
#pragma unroll
  for (int i = 0; i < 8; ++i) {
    int p = i * 256 + tid;
    int r = p >> 4, c4 = (p & 15) << 2;
    *(float4*)&Ws[r * 64 + c4] = *(const float4*)(w2 + (size_t)r * 64 + c4);
  }
  __syncthreads();
  int r2 = (tid >> 4) << 1;
  int c2 = (tid & 15) << 2;
  float a2[2][4] = {};
#pragma unroll 4
  for (int k = 0; k < 128; ++k) {
    float4 wv = *(float4*)&Ws[k * 64 + c2];
    float x0 = H1[r2][k], x1 = H1[r2 + 1][k];
    a2[0][0] = fmaf(x0, wv.x, a2[0][0]);
    a2[0][1] = fmaf(x0, wv.y, a2[0][1]);
    a2[0][2] = fmaf(x0, wv.z, a2[0][2]);
    a2[0][3] = fmaf(x0, wv.w, a2[0][3]);
    a2[1][0] = fmaf(x1, wv.x, a2[1][0]);
    a2[1][1] = fmaf(x1, wv.y, a2[1][1]);
    a2[1][2] = fmaf(x1, wv.z, a2[1][2]);
    a2[1][3] = fmaf(x1, wv.w, a2[1][3]);
  }
#pragma unroll
  for (int i = 0; i < 2; ++i) {
    float4 o;
    o.x = fmaxf(a2[i][0] + b2[c2 + 0], 0.f);
    o.y = fmaxf(a2[i][1] + b2[c2 + 1], 0.f);
    o.z = fmaxf(a2[i][2] + b2[c2 + 2], 0.f);
    o.w = fmaxf(a2[i][3] + b2[c2 + 3], 0.f);
    *(float4*)&H2[r2 + i][c2] = o;
  }
  __syncthreads();
  // ---- layer3: [32,64]@[64,11] ----
  for (int p = tid; p < 352; p += 256) {
    int r = p / 11, c = p - (p / 11) * 11;
    float acc = b3[c];
#pragma unroll 8
    for (int k = 0; k < 64; ++k) acc = fmaf(H2[r][k], W3s[k][c], acc);
    if (m0 + r < NG) out[(size_t)(m0 + r) * 11 + c] = acc;
  }
}

extern "C" void kernel_launch(void* const* d_in, const int* in_sizes, int n_in,
                              void* d_out, int out_size, void* d_ws, size_t ws_size,
                              hipStream_t stream) {
  const float* x      = (const float*)d_in[0];
  const int*   ei     = (const int*)d_in[1];
  const int*   batch  = (const int*)d_in[2];
  const float* node_w = (const float*)d_in[3];
  const float* node_b = (const float*)d_in[4];
  const float* vn_w   = (const float*)d_in[5];
  const float* gin_w1 = (const float*)d_in[6];
  const float* gin_b1 = (const float*)d_in[7];
  const float* gin_w2 = (const float*)d_in[8];
  const float* gin_b2 = (const float*)d_in[9];
  const float* bn_g   = (const float*)d_in[10];
  const float* bn_b   = (const float*)d_in[11];
  const float* bn_m   = (const float*)d_in[12];
  const float* bn_v   = (const float*)d_in[13];
  const float* vn_w1  = (const float*)d_in[14];
  const float* vn_b1  = (const float*)d_in[15];
  const float* vbn1g  = (const float*)d_in[16];
  const float* vbn1b  = (const float*)d_in[17];
  const float* vbn1m  = (const float*)d_in[18];
  const float* vbn1v  = (const float*)d_in[19];
  const float* vn_w2  = (const float*)d_in[20];
  const float* vn_b2  = (const float*)d_in[21];
  const float* vbn2g  = (const float*)d_in[22];
  const float* vbn2b  = (const float*)d_in[23];
  const float* vbn2m  = (const float*)d_in[24];
  const float* vbn2v  = (const float*)d_in[25];
  const float* head_w1 = (const float*)d_in[26];
  const float* head_b1 = (const float*)d_in[27];
  const float* head_w2 = (const float*)d_in[28];
  const float* head_b2 = (const float*)d_in[29];
  const float* head_w3 = (const float*)d_in[30];
  const float* head_b3 = (const float*)d_in[31];

  // ---- workspace layout (~162 MB) ----
  unsigned short* h16   = (unsigned short*)d_ws;          // [NN*DD]
  unsigned short* z16   = h16 + (size_t)NN * DD;          // [NN*DD]
  unsigned short* hid16 = z16 + (size_t)NN * DD;          // [NN*DD]
  unsigned short* vnb   = hid16 + (size_t)NN * DD;        // [NG*DD]
  unsigned short* t0b   = vnb + (size_t)NG * DD;          // [NG*DD]
  unsigned short* t1b   = t0b + (size_t)NG * DD;          // [NG*DD]
  unsigned short* wf1   = t1b + (size_t)NG * DD;          // [5*65536]
  unsigned short* wf2   = wf1 + 5 * 65536;                // [5*65536]
  unsigned short* wfv1  = wf2 + 5 * 65536;                // [4*65536]
  unsigned short* wfv2  = wfv1 + 4 * 65536;               // [4*65536]
  float* t0   = (float*)(wfv2 + 4 * 65536);               // [NG*DD] fp32 pool acc
  int* rowptr = (int*)(t0 + (size_t)NG * DD);             // [NN+1]
  int* cursor = rowptr + NN + 1;                          // [NN]
  int* ssrc   = cursor + NN;                              // [NE]
  int* bsum   = ssrc + NE;                                // [128]
  int* bbase  = bsum + 128;                               // [128]

  const int* src = ei;
  const int* dst = ei + NE;

  const int NGD  = NG * DD;
  const int NGD4 = NGD / 4;
  const int NB = (NN + 1023) / 1024;  // 98

  // ---- once per launch: weight pack + CSR ----
  k_pack_w<<<(5 * 65536 + 255) / 256, 256, 0, stream>>>(gin_w1, wf1, 5);
  k_pack_w<<<(5 * 65536 + 255) / 256, 256, 0, stream>>>(gin_w2, wf2, 5);
  k_pack_w<<<(4 * 65536 + 255) / 256, 256, 0, stream>>>(vn_w1, wfv1, 4);
  k_pack_w<<<(4 * 65536 + 255) / 256, 256, 0, stream>>>(vn_w2, wfv2, 4);
  k_zeroi<<<(NN + 255) / 256, 256, 0, stream>>>(cursor, NN);
  k_hist<<<(NE + 255) / 256, 256, 0, stream>>>(dst, cursor);
  k_bsum<<<NB, 1024, 0, stream>>>(cursor, bsum);
  k_scanb<<<1, 128, 0, stream>>>(bsum, bbase, NB);
  k_rowptr<<<NB, 1024, 0, stream>>>(cursor, bbase, rowptr, cursor);
  k_fill_src<<<(NE + 255) / 256, 256, 0, stream>>>(src, dst, cursor, ssrc);

  k_node_encode<<<NN / 4, 256, 0, stream>>>(x, node_w, node_b, h16);
  k_vn_init<<<NGD / 256, 256, 0, stream>>>(vn_w, vnb);

  const int GM_NN = (NN + 63) / 64;   // 1563
  const int GM_NG = (NG + 63) / 64;   // 32

  for (int l = 0; l < NL; ++l) {
    k_aggregate_vn<<<(NN + 3) / 4, 256, 0, stream>>>(h16, vnb, batch, rowptr, ssrc, z16);
    // hid = relu(z @ W1 + b1)
    k_gemm_mfma<0><<<GM_NN, 256, 0, stream>>>(
        z16, wf1 + (size_t)l * 65536, gin_b1 + l * DD,
        nullptr, nullptr, nullptr, nullptr, hid16, NN);
    // h = leaky(bn(hid @ W2 + b2))
    k_gemm_mfma<1><<<GM_NN, 256, 0, stream>>>(
        hid16, wf2 + (size_t)l * 65536, gin_b2 + l * DD,
        bn_g + l * DD, bn_b + l * DD, bn_m + l * DD, bn_v + l * DD, h16, NN);
    if (l < NL - 1) {
      k_bf2f<<<NGD / 256, 256, 0, stream>>>(vnb, t0, NGD);       // t0 = vn
      k_pool<<<(NN + 127) / 128, 256, 0, stream>>>(h16, batch, t0);
      k_f2bf<<<NGD / 256, 256, 0, stream>>>(t0, t0b, NGD);
      // t1 = relu(bn(t0 @ vn_w1 + vn_b1))
      k_gemm_mfma<2><<<GM_NG, 256, 0, stream>>>(
          t0b, wfv1 + (size_t)l * 65536, vn_b1 + l * DD,
          vbn1g + l * DD, vbn1b + l * DD, vbn1m + l * DD, vbn1v + l * DD, t1b, NG);
      // vn = relu(bn(t1 @ vn_w2 + vn_b2))
      k_gemm_mfma<2><<<GM_NG, 256, 0, stream>>>(
          t1b, wfv2 + (size_t)l * 65536, vn_b2 + l * DD,
          vbn2g + l * DD, vbn2b + l * DD, vbn2m + l * DD, vbn2v + l * DD, vnb, NG);
    }
  }
  k_zero4<<<(NGD4 + 255) / 256, 256, 0, stream>>>((float4*)t0, NGD4);
  k_pool<<<(NN + 127) / 128, 256, 0, stream>>>(h16, batch, t0);
  k_head<<<(NG + 31) / 32, 256, 0, stream>>>(
      t0, head_w1, head_b1, head_w2, head_b2, head_w3, head_b3, (float*)d_out);
}

// Round 7
// 1183.643 us; speedup vs baseline: 6.7682x; 1.0812x over previous
//
#include <hip/hip_runtime.h>
#include <hip/hip_bf16.h>

#define NN 100000
#define NE 300000
#define NG 2000
#define DD 256
#define NL 5
#define BN_EPS 1e-5f

typedef __bf16 bf16x8 __attribute__((ext_vector_type(8)));
typedef float floatx16 __attribute__((ext_vector_type(16)));

__device__ inline unsigned short f2bf(float x) {
  unsigned int u = __builtin_bit_cast(unsigned int, x);
  unsigned int r = u + 0x7FFFu + ((u >> 16) & 1u);
  return (unsigned short)(r >> 16);
}
__device__ inline float bf2f(unsigned short u) {
  return __builtin_bit_cast(float, (unsigned int)u << 16);
}
__device__ inline float4 bfu4(ushort4 u) {
  return make_float4(bf2f(u.x), bf2f(u.y), bf2f(u.z), bf2f(u.w));
}
__device__ inline float blo(unsigned int v) {
  return __builtin_bit_cast(float, v << 16);
}
__device__ inline float bhi(unsigned int v) {
  return __builtin_bit_cast(float, v & 0xFFFF0000u);
}
__device__ inline unsigned int pack2(float a, float b) {
  return (unsigned int)f2bf(a) | ((unsigned int)f2bf(b) << 16);
}

// ---------------- utility ----------------
__global__ __launch_bounds__(256) void k_zeroi(int* __restrict__ p, int n) {
  int i = blockIdx.x * 256 + threadIdx.x;
  if (i < n) p[i] = 0;
}

// ---------------- weight pack: W[k][n] fp32 (256x256) -> fragment-major bf16 -------
__global__ __launch_bounds__(256) void k_pack_w(const float* __restrict__ W,
                                                unsigned short* __restrict__ Wf,
                                                int nmat) {
  int idx = blockIdx.x * 256 + threadIdx.x;
  if (idx >= nmat * 65536) return;
  int m = idx >> 16, r = idx & 65535;
  int j = r & 7, lane = (r >> 3) & 63, ks = (r >> 9) & 15, nt = r >> 13;
  int n = nt * 32 + (lane & 31);
  int k = ks * 16 + ((lane >> 5) << 3) + j;
  Wf[idx] = f2bf(W[(size_t)m * 65536 + k * 256 + n]);
}

// ---------------- CSR build ----------------
__global__ __launch_bounds__(256) void k_hist(const int* __restrict__ dst,
                                              int* __restrict__ cnt) {
  int e = blockIdx.x * 256 + threadIdx.x;
  if (e < NE) atomicAdd(&cnt[dst[e]], 1);
}

__global__ __launch_bounds__(1024) void k_bsum(const int* __restrict__ cnt,
                                               int* __restrict__ bsum) {
  __shared__ int sh[1024];
  int t = threadIdx.x, idx = blockIdx.x * 1024 + t;
  sh[t] = (idx < NN) ? cnt[idx] : 0;
  __syncthreads();
  for (int off = 512; off > 0; off >>= 1) {
    if (t < off) sh[t] += sh[t + off];
    __syncthreads();
  }
  if (t == 0) bsum[blockIdx.x] = sh[0];
}

__global__ __launch_bounds__(128) void k_scanb(const int* __restrict__ bsum,
                                               int* __restrict__ bbase, int nb) {
  __shared__ int sh[128];
  int t = threadIdx.x;
  sh[t] = (t < nb) ? bsum[t] : 0;
  __syncthreads();
  if (t == 0) {
    int run = 0;
    for (int i = 0; i < nb; ++i) { int v = sh[i]; sh[i] = run; run += v; }
  }
  __syncthreads();
  if (t < nb) bbase[t] = sh[t];
}

__global__ __launch_bounds__(1024) void k_rowptr(const int* __restrict__ cnt,
                                                 const int* __restrict__ bbase,
                                                 int* __restrict__ rowptr,
                                                 int* __restrict__ cursor) {
  __shared__ int sh[1024];
  int t = threadIdx.x, idx = blockIdx.x * 1024 + t;
  int v = (idx < NN) ? cnt[idx] : 0;
  sh[t] = v;
  __syncthreads();
  for (int off = 1; off < 1024; off <<= 1) {
    int add = (t >= off) ? sh[t - off] : 0;
    __syncthreads();
    sh[t] += add;
    __syncthreads();
  }
  if (idx < NN) {
    int excl = sh[t] - v + bbase[blockIdx.x];
    rowptr[idx] = excl;
    cursor[idx] = excl;
  }
  if (blockIdx.x == 0 && t == 0) rowptr[NN] = NE;
}

__global__ __launch_bounds__(256) void k_fill_src(const int* __restrict__ src,
                                                  const int* __restrict__ dst,
                                                  int* __restrict__ cursor,
                                                  int* __restrict__ ssrc) {
  int e = blockIdx.x * 256 + threadIdx.x;
  if (e >= NE) return;
  int pos = atomicAdd(&cursor[dst[e]], 1);
  ssrc[pos] = src[e];
}

// ---------------- graph bounds from sorted batch (no atomics) ----------------
__global__ __launch_bounds__(256) void k_gbounds(const int* __restrict__ batch,
                                                 int* __restrict__ gstart,
                                                 int* __restrict__ gend) {
  int n = blockIdx.x * 256 + threadIdx.x;
  if (n >= NN) return;
  int b = batch[n];
  if (n == 0 || batch[n - 1] != b) gstart[b] = n;
  if (n == NN - 1 || batch[n + 1] != b) gend[b] = n + 1;
}

// ---------------- node encode -> bf16 (16 nodes/block, w in LDS) ----------------
__global__ __launch_bounds__(256) void k_node_encode(
    const float* __restrict__ x, const float* __restrict__ w,
    const float* __restrict__ b, unsigned short* __restrict__ h16) {
  __shared__ float ws[20][256];
  __shared__ float xr[16][20];
  int tid = threadIdx.x;
  int n0 = blockIdx.x * 16;
  for (int p = tid; p < 20 * 64; p += 256) {
    int k = p >> 6, c4 = (p & 63) << 2;
    *(float4*)&ws[k][c4] = *(const float4*)(w + k * 256 + c4);
  }
  for (int p = tid; p < 320; p += 256) {
    int nn = p / 20, k = p - nn * 20;
    xr[nn][k] = x[(size_t)(n0 + nn) * 20 + k];
  }
  __syncthreads();
  int ln = tid >> 6, c4 = (tid & 63) << 2;
  float4 bv = *(const float4*)(b + c4);
  float a[4][4];
#pragma unroll
  for (int nn = 0; nn < 4; ++nn) {
    a[nn][0] = bv.x; a[nn][1] = bv.y; a[nn][2] = bv.z; a[nn][3] = bv.w;
  }
#pragma unroll
  for (int k = 0; k < 20; ++k) {
    float4 wv = *(float4*)&ws[k][c4];
#pragma unroll
    for (int nn = 0; nn < 4; ++nn) {
      float xv = xr[ln * 4 + nn][k];
      a[nn][0] = fmaf(xv, wv.x, a[nn][0]);
      a[nn][1] = fmaf(xv, wv.y, a[nn][1]);
      a[nn][2] = fmaf(xv, wv.z, a[nn][2]);
      a[nn][3] = fmaf(xv, wv.w, a[nn][3]);
    }
  }
#pragma unroll
  for (int nn = 0; nn < 4; ++nn) {
    int n = n0 + ln * 4 + nn;
    *(ushort4*)(h16 + (size_t)n * DD + c4) =
        make_ushort4(f2bf(a[nn][0]), f2bf(a[nn][1]), f2bf(a[nn][2]), f2bf(a[nn][3]));
  }
}

__global__ __launch_bounds__(256) void k_vn_init(const float* __restrict__ vnw,
                                                 unsigned short* __restrict__ vnb) {
  int i = blockIdx.x * 256 + threadIdx.x;
  vnb[i] = f2bf(vnw[i & (DD - 1)]);
}

// ---------------- u = h + vn[batch]  (streaming, bf16 in/out) ----------------
__global__ __launch_bounds__(256) void k_addvn_u(
    const unsigned short* __restrict__ h16, const unsigned short* __restrict__ vnb,
    const int* __restrict__ batch, unsigned short* __restrict__ u16) {
  int idx = blockIdx.x * 256 + threadIdx.x;      // uint4 index
  int n = idx >> 5, c8 = (idx & 31) << 3;
  int g = batch[n];
  uint4 hv = ((const uint4*)h16)[idx];
  uint4 vv = *(const uint4*)(vnb + (size_t)g * DD + c8);
  uint4 o;
  o.x = pack2(blo(hv.x) + blo(vv.x), bhi(hv.x) + bhi(vv.x));
  o.y = pack2(blo(hv.y) + blo(vv.y), bhi(hv.y) + bhi(vv.y));
  o.z = pack2(blo(hv.z) + blo(vv.z), bhi(hv.z) + bhi(vv.z));
  o.w = pack2(blo(hv.w) + blo(vv.w), bhi(hv.w) + bhi(vv.w));
  ((uint4*)u16)[idx] = o;
}

// ---------------- segment pool: one block per graph, no atomics ----------------
// MODE 0: bf16 out = sum + vn (VN-MLP input); MODE 1: fp32 out = sum (head input)
template <int MODE>
__global__ __launch_bounds__(256) void k_pool_seg(
    const unsigned short* __restrict__ h16, const unsigned short* __restrict__ vnb,
    const int* __restrict__ gstart, const int* __restrict__ gend,
    unsigned short* __restrict__ outb, float* __restrict__ outf) {
  __shared__ float4 sh[4][64];
  int g = blockIdx.x;
  int lane = threadIdx.x & 63, grp = threadIdx.x >> 6;
  int c4 = lane << 2;
  int s = gstart[g], e = gend[g];
  float4 acc = make_float4(0.f, 0.f, 0.f, 0.f);
  for (int n = s + grp; n < e; n += 4) {
    float4 v = bfu4(*(const ushort4*)(h16 + (size_t)n * DD + c4));
    acc.x += v.x; acc.y += v.y; acc.z += v.z; acc.w += v.w;
  }
  sh[grp][lane] = acc;
  __syncthreads();
  if (grp == 0) {
    float4 a0 = sh[0][lane], a1 = sh[1][lane], a2 = sh[2][lane], a3 = sh[3][lane];
    acc.x = a0.x + a1.x + a2.x + a3.x;
    acc.y = a0.y + a1.y + a2.y + a3.y;
    acc.z = a0.z + a1.z + a2.z + a3.z;
    acc.w = a0.w + a1.w + a2.w + a3.w;
    if (MODE == 0) {
      float4 v = bfu4(*(const ushort4*)(vnb + (size_t)g * DD + c4));
      acc.x += v.x; acc.y += v.y; acc.z += v.z; acc.w += v.w;
      *(ushort4*)(outb + (size_t)g * DD + c4) =
          make_ushort4(f2bf(acc.x), f2bf(acc.y), f2bf(acc.z), f2bf(acc.w));
    } else {
      *(float4*)(outf + (size_t)g * DD + c4) = acc;
    }
  }
}

// ---------------- fused gather-GEMM (GIN layer 1): ----------------
// A-tile row m: z = u[m] + sum_{src in CSR[m]} u[src]; C = relu(z @ W + bias)
__global__ __launch_bounds__(256) void k_gemm_gather(
    const unsigned short* __restrict__ u16, const int* __restrict__ rowptr,
    const int* __restrict__ ssrc, const unsigned short* __restrict__ Wf,
    const float* __restrict__ bias, unsigned short* __restrict__ C16) {
  __shared__ unsigned short As[2][16][2][32][8];  // 32 KB
  int tid = threadIdx.x;
  int m0 = blockIdx.x * 64;
  int r = tid & 63, q = tid >> 6;
  int m = m0 + r;
  int cb = q << 6;  // 64-col chunk base
  float acc[64];
#pragma unroll
  for (int i = 0; i < 64; ++i) acc[i] = 0.f;
  if (m < NN) {
    const unsigned short* up = u16 + (size_t)m * DD + cb;
#pragma unroll
    for (int i = 0; i < 8; ++i) {
      uint4 v = *(const uint4*)(up + i * 8);
      acc[i * 8 + 0] = blo(v.x); acc[i * 8 + 1] = bhi(v.x);
      acc[i * 8 + 2] = blo(v.y); acc[i * 8 + 3] = bhi(v.y);
      acc[i * 8 + 4] = blo(v.z); acc[i * 8 + 5] = bhi(v.z);
      acc[i * 8 + 6] = blo(v.w); acc[i * 8 + 7] = bhi(v.w);
    }
    int b = rowptr[m], e = rowptr[m + 1];
    for (int t = b; t < e; ++t) {
      int s = ssrc[t];
      const unsigned short* sp = u16 + (size_t)s * DD + cb;
#pragma unroll
      for (int i = 0; i < 8; ++i) {
        uint4 v = *(const uint4*)(sp + i * 8);
        acc[i * 8 + 0] += blo(v.x); acc[i * 8 + 1] += bhi(v.x);
        acc[i * 8 + 2] += blo(v.y); acc[i * 8 + 3] += bhi(v.y);
        acc[i * 8 + 4] += blo(v.z); acc[i * 8 + 5] += bhi(v.z);
        acc[i * 8 + 6] += blo(v.w); acc[i * 8 + 7] += bhi(v.w);
      }
    }
  }
  // pack to LDS fragments
#pragma unroll
  for (int i = 0; i < 8; ++i) {
    int c0 = cb + i * 8;
    uint4 o;
    o.x = pack2(acc[i * 8 + 0], acc[i * 8 + 1]);
    o.y = pack2(acc[i * 8 + 2], acc[i * 8 + 3]);
    o.z = pack2(acc[i * 8 + 4], acc[i * 8 + 5]);
    o.w = pack2(acc[i * 8 + 6], acc[i * 8 + 7]);
    *(uint4*)&As[r >> 5][c0 >> 4][(c0 >> 3) & 1][r & 31][0] = o;
  }
  __syncthreads();

  int wave = tid >> 6, lane = tid & 63;
  int wm = wave & 1, nhalf = wave >> 1;
  int lrow = lane & 31, lhi = lane >> 5;

  floatx16 facc[4];
#pragma unroll
  for (int j = 0; j < 4; ++j) facc[j] = (floatx16)(0.f);

  const bf16x8* wf = (const bf16x8*)Wf;
#pragma unroll
  for (int ks = 0; ks < 16; ++ks) {
    bf16x8 a = *(const bf16x8*)&As[wm][ks][lhi][lrow][0];
#pragma unroll
    for (int j = 0; j < 4; ++j) {
      int nt = nhalf * 4 + j;
      bf16x8 bb = wf[((nt * 16 + ks) << 6) + lane];
      facc[j] = __builtin_amdgcn_mfma_f32_32x32x16_bf16(a, bb, facc[j], 0, 0, 0);
    }
  }
#pragma unroll
  for (int j = 0; j < 4; ++j) {
    int ncol = nhalf * 128 + j * 32 + lrow;
    float shf = bias[ncol];
#pragma unroll
    for (int reg = 0; reg < 16; ++reg) {
      int row = (reg & 3) + ((reg >> 2) << 3) + (lhi << 2);
      int mm = m0 + wm * 32 + row;
      if (mm < NN) {
        float v = fmaxf(facc[j][reg] + shf, 0.f);
        C16[(size_t)mm * DD + ncol] = f2bf(v);
      }
    }
  }
}

// ---------------- MFMA GEMM: bf16 A [M,256] x packed bf16 W -> bf16 C ----------------
// EPI: 0 = relu(v+bias); 1 = leaky0.1(bn(v+bias)); 2 = relu(bn(v+bias))
template <int EPI>
__global__ __launch_bounds__(256) void k_gemm_mfma(
    const unsigned short* __restrict__ A16, const unsigned short* __restrict__ Wf,
    const float* __restrict__ bias,
    const float* __restrict__ bng, const float* __restrict__ bnb,
    const float* __restrict__ bnm, const float* __restrict__ bnv,
    unsigned short* __restrict__ C16, int Mtot) {
  __shared__ unsigned short As[2][16][2][32][8];  // 32 KB
  int tid = threadIdx.x;
  int m0 = blockIdx.x * 64;
#pragma unroll
  for (int i = 0; i < 8; ++i) {
    int qq = i * 256 + tid;
    int lr = qq & 31, lh = (qq >> 5) & 1, ks = (qq >> 6) & 15, wm = qq >> 10;
    int m = m0 + wm * 32 + lr;
    uint4 v = make_uint4(0u, 0u, 0u, 0u);
    if (m < Mtot) v = *(const uint4*)(A16 + (size_t)m * DD + ks * 16 + lh * 8);
    *(uint4*)&As[wm][ks][lh][lr][0] = v;
  }
  __syncthreads();

  int wave = tid >> 6, lane = tid & 63;
  int wm = wave & 1, nhalf = wave >> 1;
  int lrow = lane & 31, lhi = lane >> 5;

  floatx16 acc[4];
#pragma unroll
  for (int j = 0; j < 4; ++j) acc[j] = (floatx16)(0.f);

  const bf16x8* wf = (const bf16x8*)Wf;
#pragma unroll
  for (int ks = 0; ks < 16; ++ks) {
    bf16x8 a = *(const bf16x8*)&As[wm][ks][lhi][lrow][0];
#pragma unroll
    for (int j = 0; j < 4; ++j) {
      int nt = nhalf * 4 + j;
      bf16x8 b = wf[((nt * 16 + ks) << 6) + lane];
      acc[j] = __builtin_amdgcn_mfma_f32_32x32x16_bf16(a, b, acc[j], 0, 0, 0);
    }
  }

#pragma unroll
  for (int j = 0; j < 4; ++j) {
    int ncol = nhalf * 128 + j * 32 + lrow;
    float scl, shf;
    float bsv = bias[ncol];
    if (EPI >= 1) {
      float s = bng[ncol] * rsqrtf(bnv[ncol] + BN_EPS);
      scl = s;
      shf = bsv * s + bnb[ncol] - bnm[ncol] * s;
    } else {
      scl = 1.f;
      shf = bsv;
    }
#pragma unroll
    for (int reg = 0; reg < 16; ++reg) {
      int row = (reg & 3) + ((reg >> 2) << 3) + (lhi << 2);
      int m = m0 + wm * 32 + row;
      if (m < Mtot) {
        float v = acc[j][reg] * scl + shf;
        if (EPI == 1) v = (v > 0.f) ? v : 0.1f * v;
        else v = fmaxf(v, 0.f);
        C16[(size_t)m * DD + ncol] = f2bf(v);
      }
    }
  }
}

// ---------------- fused head: out = relu(relu(g@W1+b1)@W2+b2)@W3+b3, all fp32 -------
__global__ __launch_bounds__(256) void k_head(
    const float* __restrict__ X,
    const float* __restrict__ w1, const float* __restrict__ b1,
    const float* __restrict__ w2, const float* __restrict__ b2,
    const float* __restrict__ w3, const float* __restrict__ b3,
    float* __restrict__ out) {
  __shared__ float Xs[32][260];
  __shared__ float Ws[8192];
  __shared__ float H1[32][132];
  __shared__ float H2[32][68];
  __shared__ float W3s[64][12];
  int tid = threadIdx.x;
  int m0 = blockIdx.x * 32;
#pragma unroll
  for (int i = 0; i < 8; ++i) {
    int p = i * 256 + tid;
    int r = p >> 6, c4 = (p & 63) << 2;
    float4 v = make_float4(0.f, 0.f, 0.f, 0.f);
    if (m0 + r < NG) v = *(const float4*)(X + (size_t)(m0 + r) * 256 + c4);
    *(float4*)&Xs[r][c4] = v;
  }
  for (int p = tid; p < 704; p += 256) W3s[p / 11][p % 11] = w3[p];

  int r0 = (tid >> 5) << 2;
  int c0 = (tid & 31) << 2;
  float a1[4][4] = {};
  for (int k0 = 0; k0 < 256; k0 += 64) {
    __syncthreads();
#pragma unroll
    for (int i = 0; i < 8; ++i) {
      int p = i * 256 + tid;
      int r = p >> 5, c4 = (p & 31) << 2;
      *(float4*)&Ws[r * 128 + c4] = *(const float4*)(w1 + (size_t)(k0 + r) * 128 + c4);
    }
    __syncthreads();
#pragma unroll 4
    for (int k = 0; k < 64; ++k) {
      float4 wv = *(float4*)&Ws[k * 128 + c0];
      float xv[4];
#pragma unroll
      for (int i = 0; i < 4; ++i) xv[i] = Xs[r0 + i][k0 + k];
#pragma unroll
      for (int i = 0; i < 4; ++i) {
        a1[i][0] = fmaf(xv[i], wv.x, a1[i][0]);
        a1[i][1] = fmaf(xv[i], wv.y, a1[i][1]);
        a1[i][2] = fmaf(xv[i], wv.z, a1[i][2]);
        a1[i][3] = fmaf(xv[i], wv.w, a1[i][3]);
      }
    }
  }
#pragma unroll
  for (int i = 0; i < 4; ++i) {
    float4 o;
    o.x = fmaxf(a1[i][0] + b1[c0 + 0], 0.f);
    o.y = fmaxf(a1[i][1] + b1[c0 + 1], 0.f);
    o.z = fmaxf(a1[i][2] + b1[c0 + 2], 0.f);
    o.w = fmaxf(a1[i][3] + b1[c0 + 3], 0.f);
    *(float4*)&H1[r0 + i][c0] = o;
  }
  __syncthreads();
#pragma unroll
  for (int i = 0; i < 8; ++i) {
    int p = i * 256 + tid;
    int r = p >> 4, c4 = (p & 15) << 2;
    *(float4*)&Ws[r * 64 + c4] = *(const float4*)(w2 + (size_t)r * 64 + c4);
  }
  __syncthreads();
  int r2 = (tid >> 4) << 1;
  int c2 = (tid & 15) << 2;
  float a2[2][4] = {};
#pragma unroll 4
  for (int k = 0; k < 128; ++k) {
    float4 wv = *(float4*)&Ws[k * 64 + c2];
    float x0 = H1[r2][k], x1 = H1[r2 + 1][k];
    a2[0][0] = fmaf(x0, wv.x, a2[0][0]);
    a2[0][1] = fmaf(x0, wv.y, a2[0][1]);
    a2[0][2] = fmaf(x0, wv.z, a2[0][2]);
    a2[0][3] = fmaf(x0, wv.w, a2[0][3]);
    a2[1][0] = fmaf(x1, wv.x, a2[1][0]);
    a2[1][1] = fmaf(x1, wv.y, a2[1][1]);
    a2[1][2] = fmaf(x1, wv.z, a2[1][2]);
    a2[1][3] = fmaf(x1, wv.w, a2[1][3]);
  }
#pragma unroll
  for (int i = 0; i < 2; ++i) {
    float4 o;
    o.x = fmaxf(a2[i][0] + b2[c2 + 0], 0.f);
    o.y = fmaxf(a2[i][1] + b2[c2 + 1], 0.f);
    o.z = fmaxf(a2[i][2] + b2[c2 + 2], 0.f);
    o.w = fmaxf(a2[i][3] + b2[c2 + 3], 0.f);
    *(float4*)&H2[r2 + i][c2] = o;
  }
  __syncthreads();
  for (int p = tid; p < 352; p += 256) {
    int r = p / 11, c = p - (p / 11) * 11;
    float acc = b3[c];
#pragma unroll 8
    for (int k = 0; k < 64; ++k) acc = fmaf(H2[r][k], W3s[k][c], acc);
    if (m0 + r < NG) out[(size_t)(m0 + r) * 11 + c] = acc;
  }
}

extern "C" void kernel_launch(void* const* d_in, const int* in_sizes, int n_in,
                              void* d_out, int out_size, void* d_ws, size_t ws_size,
                              hipStream_t stream) {
  const float* x      = (const float*)d_in[0];
  const int*   ei     = (const int*)d_in[1];
  const int*   batch  = (const int*)d_in[2];
  const float* node_w = (const float*)d_in[3];
  const float* node_b = (const float*)d_in[4];
  const float* vn_w   = (const float*)d_in[5];
  const float* gin_w1 = (const float*)d_in[6];
  const float* gin_b1 = (const float*)d_in[7];
  const float* gin_w2 = (const float*)d_in[8];
  const float* gin_b2 = (const float*)d_in[9];
  const float* bn_g   = (const float*)d_in[10];
  const float* bn_b   = (const float*)d_in[11];
  const float* bn_m   = (const float*)d_in[12];
  const float* bn_v   = (const float*)d_in[13];
  const float* vn_w1  = (const float*)d_in[14];
  const float* vn_b1  = (const float*)d_in[15];
  const float* vbn1g  = (const float*)d_in[16];
  const float* vbn1b  = (const float*)d_in[17];
  const float* vbn1m  = (const float*)d_in[18];
  const float* vbn1v  = (const float*)d_in[19];
  const float* vn_w2  = (const float*)d_in[20];
  const float* vn_b2  = (const float*)d_in[21];
  const float* vbn2g  = (const float*)d_in[22];
  const float* vbn2b  = (const float*)d_in[23];
  const float* vbn2m  = (const float*)d_in[24];
  const float* vbn2v  = (const float*)d_in[25];
  const float* head_w1 = (const float*)d_in[26];
  const float* head_b1 = (const float*)d_in[27];
  const float* head_w2 = (const float*)d_in[28];
  const float* head_b2 = (const float*)d_in[29];
  const float* head_w3 = (const float*)d_in[30];
  const float* head_b3 = (const float*)d_in[31];

  // ---- workspace layout (~160 MB) ----
  unsigned short* h16   = (unsigned short*)d_ws;          // [NN*DD]
  unsigned short* u16   = h16 + (size_t)NN * DD;          // [NN*DD]
  unsigned short* hid16 = u16 + (size_t)NN * DD;          // [NN*DD]
  unsigned short* vnb   = hid16 + (size_t)NN * DD;        // [NG*DD]
  unsigned short* t0b   = vnb + (size_t)NG * DD;          // [NG*DD]
  unsigned short* t1b   = t0b + (size_t)NG * DD;          // [NG*DD]
  unsigned short* wf1   = t1b + (size_t)NG * DD;          // [5*65536]
  unsigned short* wf2   = wf1 + 5 * 65536;                // [5*65536]
  unsigned short* wfv1  = wf2 + 5 * 65536;                // [4*65536]
  unsigned short* wfv2  = wfv1 + 4 * 65536;               // [4*65536]
  float* t0f  = (float*)(wfv2 + 4 * 65536);               // [NG*DD]
  int* rowptr = (int*)(t0f + (size_t)NG * DD);            // [NN+1]
  int* cursor = rowptr + NN + 1;                          // [NN]
  int* ssrc   = cursor + NN;                              // [NE]
  int* bsum   = ssrc + NE;                                // [128]
  int* bbase  = bsum + 128;                               // [128]
  int* gstart = bbase + 128;                              // [NG]
  int* gend   = gstart + NG;                              // [NG]

  const int* src = ei;
  const int* dst = ei + NE;

  const int NB = (NN + 1023) / 1024;  // 98

  // ---- once per launch: weight pack + CSR + graph bounds ----
  k_pack_w<<<(5 * 65536 + 255) / 256, 256, 0, stream>>>(gin_w1, wf1, 5);
  k_pack_w<<<(5 * 65536 + 255) / 256, 256, 0, stream>>>(gin_w2, wf2, 5);
  k_pack_w<<<(4 * 65536 + 255) / 256, 256, 0, stream>>>(vn_w1, wfv1, 4);
  k_pack_w<<<(4 * 65536 + 255) / 256, 256, 0, stream>>>(vn_w2, wfv2, 4);
  k_zeroi<<<(NN + 255) / 256, 256, 0, stream>>>(cursor, NN);
  k_hist<<<(NE + 255) / 256, 256, 0, stream>>>(dst, cursor);
  k_bsum<<<NB, 1024, 0, stream>>>(cursor, bsum);
  k_scanb<<<1, 128, 0, stream>>>(bsum, bbase, NB);
  k_rowptr<<<NB, 1024, 0, stream>>>(cursor, bbase, rowptr, cursor);
  k_fill_src<<<(NE + 255) / 256, 256, 0, stream>>>(src, dst, cursor, ssrc);
  k_zeroi<<<(2 * NG + 255) / 256, 256, 0, stream>>>(gstart, 2 * NG);  // gstart+gend
  k_gbounds<<<(NN + 255) / 256, 256, 0, stream>>>(batch, gstart, gend);

  k_node_encode<<<NN / 16, 256, 0, stream>>>(x, node_w, node_b, h16);
  k_vn_init<<<NG * DD / 256, 256, 0, stream>>>(vn_w, vnb);

  const int GM_NN = (NN + 63) / 64;   // 1563
  const int GM_NG = (NG + 63) / 64;   // 32
  const int NU4   = NN * DD / 8;      // uint4 count

  for (int l = 0; l < NL; ++l) {
    // u = h + vn[batch]
    k_addvn_u<<<NU4 / 256, 256, 0, stream>>>(h16, vnb, batch, u16);
    // hid = relu((u[m] + sum u[src]) @ W1 + b1)  [fused gather]
    k_gemm_gather<<<GM_NN, 256, 0, stream>>>(
        u16, rowptr, ssrc, wf1 + (size_t)l * 65536, gin_b1 + l * DD, hid16);
    // h = leaky(bn(hid @ W2 + b2))
    k_gemm_mfma<1><<<GM_NN, 256, 0, stream>>>(
        hid16, wf2 + (size_t)l * 65536, gin_b2 + l * DD,
        bn_g + l * DD, bn_b + l * DD, bn_m + l * DD, bn_v + l * DD, h16, NN);
    if (l < NL - 1) {
      // t0 = pool(h) + vn  (bf16)
      k_pool_seg<0><<<NG, 256, 0, stream>>>(h16, vnb, gstart, gend, t0b, nullptr);
      k_gemm_mfma<2><<<GM_NG, 256, 0, stream>>>(
          t0b, wfv1 + (size_t)l * 65536, vn_b1 + l * DD,
          vbn1g + l * DD, vbn1b + l * DD, vbn1m + l * DD, vbn1v + l * DD, t1b, NG);
      k_gemm_mfma<2><<<GM_NG, 256, 0, stream>>>(
          t1b, wfv2 + (size_t)l * 65536, vn_b2 + l * DD,
          vbn2g + l * DD, vbn2b + l * DD, vbn2m + l * DD, vbn2v + l * DD, vnb, NG);
    }
  }
  // final pool (fp32, no vn) + fused head
  k_pool_seg<1><<<NG, 256, 0, stream>>>(h16, nullptr, gstart, gend, nullptr, t0f);
  k_head<<<(NG + 31) / 32, 256, 0, stream>>>(
      t0f, head_w1, head_b1, head_w2, head_b2, head_w3, head_b3, (float*)d_out);
}